// Round 4
// baseline (716.364 us; speedup 1.0000x reference)
//
#include <hip/hip_runtime.h>

#define BDIM 4
#define CDIM 128
#define NDIM 4096
#define KSEL 10
#define MSPLIT 8
#define MT_PER (NDIM / MSPLIT / 128)  // 4 m-tiles of 128 per block

// ---------------------------------------------------------------------------
// Kernel A: xx[b][n] = sum_c x[b][c][n]^2
// ---------------------------------------------------------------------------
__global__ __launch_bounds__(256) void xx_kernel(const float* __restrict__ x,
                                                 float* __restrict__ xx) {
  int t = threadIdx.x;
  int nl = t >> 2;
  int part = t & 3;
  int g = blockIdx.x * 64 + nl;      // 0..B*N-1
  int b = g >> 12;
  int n = g & (NDIM - 1);
  const float* xp = x + (size_t)b * CDIM * NDIM + n;
  float s = 0.f;
  int c0 = part * 32;
#pragma unroll
  for (int i = 0; i < 32; ++i) {
    float v = xp[(size_t)(c0 + i) * NDIM];
    s += v * v;
  }
  s += __shfl_xor(s, 1, 4);
  s += __shfl_xor(s, 2, 4);
  if (part == 0) xx[g] = s;
}

// ---------------------------------------------------------------------------
// Kernel B: fused distance-GEMM + top-10, m-split 8 ways.
// Block = 64 rows x 512 cols (4 m-tiles of 128). 256 threads.
// GEMM: thread tile 4 rows x 8 cols (acc=32 regs, 32 FMA : 3 ds_read_b128/c).
// Scores go to LDS (sc ALIASES the xn/xm staging space, 34KB total);
// scan: 4 threads/row, one private top-10 list per thread.
// NOTE: plain __launch_bounds__(256) — the (256,4) hint made the compiler
// target 64 VGPR and spill tv/ti/acc to scratch (R3: 1 GB HBM traffic,
// spill-BW-bound at 1.84 TB/s). R1 proved this profile: 116 VGPR, no spill,
// which still fits 4 waves/EU (512/116 -> 4) = 4 blocks/CU.
// Emits per-(row,split) SORTED partial top-10 (val desc, idx asc).
// ---------------------------------------------------------------------------
__global__ __launch_bounds__(256) void topk_kernel(const float* __restrict__ x,
                                                   const float* __restrict__ xxg,
                                                   float* __restrict__ pval,
                                                   int* __restrict__ pidx) {
  const int N = NDIM;
  int bb = blockIdx.z;
  int ms = blockIdx.y;
  int n0 = blockIdx.x * 64;
  int t = threadIdx.x;
  int tx = t & 15, ty = t >> 4;
  int tx4 = tx * 4, ty4 = ty * 4;

  __shared__ float smem[8448 + 128];
  float* xn = smem;            // [32][64]   2048 f  (aliased by sc)
  float* xm = smem + 2048;     // [32][128]  4096 f  (aliased by sc)
  float* sc = smem;            // [64][132]  8448 f  (aliases xn+xm)
  float* xxs = smem + 8448;    // [128]

  const float* xb = x + (size_t)bb * CDIM * N;
  const float* xxb = xxg + (size_t)bb * N;

  // one private top-10 list per thread (static indexing only)
  float tv[KSEL];
  int ti[KSEL];
#pragma unroll
  for (int s = 0; s < KSEL; ++s) { tv[s] = -1e30f; ti[s] = 0x7fffffff; }
  float minv = -1e30f;
  int mini = 0x7fffffff;
  int minp = 0;

  // staging address precompute (linear float4 layout -> conflict-free)
  int xn_cc[2], xn_q[2], xm_cc[4], xm_q[4];
#pragma unroll
  for (int p = 0; p < 2; ++p) { int i4 = t + 256 * p; xn_cc[p] = i4 >> 4; xn_q[p] = (i4 & 15) * 4; }
#pragma unroll
  for (int p = 0; p < 4; ++p) { int i4 = t + 256 * p; xm_cc[p] = i4 >> 5; xm_q[p] = (i4 & 31) * 4; }

  int msbase = ms * (NDIM / MSPLIT);  // ms*512
  float4 pxn[2], pxm[4];
  auto issue = [&](int u) {  // u = mt*4+ch ; prefetch global->regs
    int m0u = msbase + (u >> 2) * 128;
    int c0u = (u & 3) * 32;
#pragma unroll
    for (int p = 0; p < 2; ++p)
      pxn[p] = *(const float4*)&xb[(size_t)(c0u + xn_cc[p]) * N + n0 + xn_q[p]];
#pragma unroll
    for (int p = 0; p < 4; ++p)
      pxm[p] = *(const float4*)&xb[(size_t)(c0u + xm_cc[p]) * N + m0u + xm_q[p]];
  };

  issue(0);
  const int NCHUNK = MT_PER * 4;  // 16

  for (int mt = 0; mt < MT_PER; ++mt) {
    int m0 = msbase + mt * 128;
    float acc[4][8];
#pragma unroll
    for (int i = 0; i < 4; ++i)
#pragma unroll
      for (int j = 0; j < 8; ++j) acc[i][j] = 0.f;

    for (int ch = 0; ch < 4; ++ch) {
      int u = mt * 4 + ch;
      __syncthreads();  // prior LDS consumers (prev chunk GEMM / prev mt scan)
#pragma unroll
      for (int p = 0; p < 2; ++p) *(float4*)&xn[xn_cc[p] * 64 + xn_q[p]] = pxn[p];
#pragma unroll
      for (int p = 0; p < 4; ++p) *(float4*)&xm[xm_cc[p] * 128 + xm_q[p]] = pxm[p];
      if (ch == 0 && t < 128) xxs[t] = xxb[m0 + t];
      __syncthreads();
      if (u + 1 < NCHUNK) issue(u + 1);  // overlap next stage with compute

#pragma unroll 8
      for (int cc = 0; cc < 32; ++cc) {
        // a: 4 distinct b128 addrs on distinct banks, broadcast over tx
        float4 a = *(const float4*)&xn[cc * 64 + ty4];
        // b: 16 distinct b128 addrs, 2 per 4-bank group -> free
        float4 b0 = *(const float4*)&xm[cc * 128 + tx4];
        float4 b1 = *(const float4*)&xm[cc * 128 + tx4 + 64];
        float av[4] = {a.x, a.y, a.z, a.w};
        float bv[8] = {b0.x, b0.y, b0.z, b0.w, b1.x, b1.y, b1.z, b1.w};
#pragma unroll
        for (int i = 0; i < 4; ++i)
#pragma unroll
          for (int j = 0; j < 8; ++j) acc[i][j] += av[i] * bv[j];
      }
    }

    // all xn/xm reads done; write scores over the aliased region
    __syncthreads();
    {
      float4 xq0 = *(const float4*)&xxs[tx4];
      float4 xq1 = *(const float4*)&xxs[tx4 + 64];
      float xv[8] = {xq0.x, xq0.y, xq0.z, xq0.w, xq1.x, xq1.y, xq1.z, xq1.w};
#pragma unroll
      for (int i = 0; i < 4; ++i) {
        int r = ty4 + i;
        float4 s0 = make_float4(2.f * acc[i][0] - xv[0], 2.f * acc[i][1] - xv[1],
                                2.f * acc[i][2] - xv[2], 2.f * acc[i][3] - xv[3]);
        float4 s1 = make_float4(2.f * acc[i][4] - xv[4], 2.f * acc[i][5] - xv[5],
                                2.f * acc[i][6] - xv[6], 2.f * acc[i][7] - xv[7]);
        *(float4*)&sc[r * 132 + tx4] = s0;
        *(float4*)&sc[r * 132 + tx4 + 64] = s1;
      }
    }
    __syncthreads();

    // scan: thread (rr = t>>2, q = t&3) takes cols == q (mod 4)
    // bank = (4*rr + q + 4*i) mod 32 -> exactly 2 lanes/bank = free
    {
      int rr = t >> 2, q = t & 3;
      const float* srow = &sc[rr * 132 + q];
      int gbase = m0 + q;
#pragma unroll 8
      for (int i = 0; i < 32; ++i) {
        float v = srow[4 * i];
        int gm = gbase + 4 * i;
        if (v > minv || (v == minv && gm < mini)) {
#pragma unroll
          for (int s = 0; s < KSEL; ++s)
            if (minp == s) { tv[s] = v; ti[s] = gm; }
          minv = tv[0]; mini = ti[0]; minp = 0;
#pragma unroll
          for (int s = 1; s < KSEL; ++s)
            if (tv[s] < minv || (tv[s] == minv && ti[s] > mini)) {
              minv = tv[s]; mini = ti[s]; minp = s;
            }
        }
      }
    }
    // next mt's first-chunk barrier protects sc until staging overwrites it
  }

  // ----- merge 4 partial lists per row -> sorted partial top-10 -----
  __syncthreads();
  {
    int rr = t >> 2, q = t & 3;
    float* mv = smem;                   // [64][40]
    int* mi = (int*)(smem + 2560);      // [64][40]
#pragma unroll
    for (int s = 0; s < KSEL; ++s) {
      mv[rr * 40 + q * 10 + s] = tv[s];
      mi[rr * 40 + q * 10 + s] = ti[s];
    }
  }
  __syncthreads();
  if (t < 64) {
    int row = t;
    float* mv = smem + row * 40;
    int* mi = (int*)(smem + 2560) + row * 40;
    size_t obase = ((size_t)(bb * MSPLIT + ms) * N + n0 + row) * KSEL;
    for (int s = 0; s < KSEL; ++s) {
      float bvv = -3e38f;
      int bi = 0x7fffffff, bp = 0;
      for (int j = 0; j < 40; ++j) {
        float v = mv[j];
        int id = mi[j];
        if (v > bvv || (v == bvv && id < bi)) { bvv = v; bi = id; bp = j; }
      }
      mv[bp] = -3e38f;
      pval[obase + s] = bvv;
      pidx[obase + s] = bi;
    }
  }
}

// ---------------------------------------------------------------------------
// Kernel B2: merge the 8 sorted split-partials per row -> final top-10 idx
// ---------------------------------------------------------------------------
__global__ __launch_bounds__(256) void merge_kernel(const float* __restrict__ pval,
                                                    const int* __restrict__ pidx,
                                                    int* __restrict__ idxout) {
  int g = blockIdx.x * 256 + threadIdx.x;  // 0..B*N-1
  int b = g >> 12;
  int n = g & (NDIM - 1);
  int hp[MSPLIT];
#pragma unroll
  for (int q = 0; q < MSPLIT; ++q) hp[q] = 0;
  int* op = idxout + ((size_t)b * NDIM + n) * KSEL;
  for (int s = 0; s < KSEL; ++s) {
    float bv = -3e38f; int bi = 0x7fffffff; int bq = 0;
#pragma unroll
    for (int q = 0; q < MSPLIT; ++q) {
      if (hp[q] < KSEL) {
        size_t o = ((size_t)(b * MSPLIT + q) * NDIM + n) * KSEL + hp[q];
        float v = pval[o];
        int id = pidx[o];
        if (v > bv || (v == bv && id < bi)) { bv = v; bi = id; bq = q; }
      }
    }
#pragma unroll
    for (int q = 0; q < MSPLIT; ++q)
      if (bq == q) hp[q]++;
    op[s] = bi;
  }
}

// ---------------------------------------------------------------------------
// Kernel C: Md[b][c][n] = mean_k x[b][c][idx[b][n][k]] - x[b][c][n]
// ---------------------------------------------------------------------------
__global__ __launch_bounds__(256) void gather_kernel(const float* __restrict__ x,
                                                     const int* __restrict__ idxg,
                                                     float* __restrict__ Md) {
  const int N = NDIM;
  int bb = blockIdx.y, c = blockIdx.x;
  __shared__ float row_s[NDIM];
  const float* rowg = x + (size_t)(bb * CDIM + c) * N;
  int t = threadIdx.x;
#pragma unroll
  for (int p = 0; p < 4; ++p) {
    int i4 = t + 256 * p;
    *(float4*)&row_s[i4 * 4] = *(const float4*)&rowg[i4 * 4];
  }
  __syncthreads();
  float* outp = Md + (size_t)(bb * CDIM + c) * N;
  const int* ib = idxg + (size_t)bb * N * KSEL;
  for (int p = 0; p < 16; ++p) {
    int n = t + 256 * p;
    const int* ip = ib + (size_t)n * KSEL;
    float s = 0.f;
#pragma unroll
    for (int k = 0; k < KSEL; ++k) s += row_s[ip[k]];
    outp[n] = s * 0.1f - row_s[n];
  }
}

// ---------------------------------------------------------------------------
// Kernel D: out[b][o][n] = sum_c W[o][c]*Md[b][c][n] + W[o][128+c]*x[b][c][n] + b[o]
// ---------------------------------------------------------------------------
__global__ __launch_bounds__(256) void out_kernel(const float* __restrict__ Md,
                                                  const float* __restrict__ x,
                                                  const float* __restrict__ W,
                                                  const float* __restrict__ bias,
                                                  float* __restrict__ out) {
  const int N = NDIM, O = 256;
  int bb = blockIdx.z;
  int o0 = blockIdx.y * 64;
  int n0 = blockIdx.x * 128;
  int t = threadIdx.x;
  int tx = t & 15, ty = t >> 4;
  int tx8 = tx * 8, ty4 = ty * 4;

  __shared__ float w1_s[32 * 64];    // [cc][o]
  __shared__ float w2_s[32 * 64];
  __shared__ float md_s[32 * 128];   // [cc][n]
  __shared__ float x_s[32 * 128];

  float acc[4][8];
#pragma unroll
  for (int i = 0; i < 4; ++i)
#pragma unroll
    for (int j = 0; j < 8; ++j) acc[i][j] = 0.f;

  for (int ch = 0; ch < 4; ++ch) {
    int c0 = ch * 32;
    __syncthreads();
#pragma unroll
    for (int p = 0; p < 2; ++p) {
      int i = t + 256 * p;  // 0..511
      int oo = i >> 3, q = i & 7;
      float4 v1 = *(const float4*)&W[(size_t)(o0 + oo) * 256 + c0 + q * 4];
      float4 v2 = *(const float4*)&W[(size_t)(o0 + oo) * 256 + 128 + c0 + q * 4];
      w1_s[(q * 4 + 0) * 64 + oo] = v1.x;
      w1_s[(q * 4 + 1) * 64 + oo] = v1.y;
      w1_s[(q * 4 + 2) * 64 + oo] = v1.z;
      w1_s[(q * 4 + 3) * 64 + oo] = v1.w;
      w2_s[(q * 4 + 0) * 64 + oo] = v2.x;
      w2_s[(q * 4 + 1) * 64 + oo] = v2.y;
      w2_s[(q * 4 + 2) * 64 + oo] = v2.z;
      w2_s[(q * 4 + 3) * 64 + oo] = v2.w;
    }
#pragma unroll
    for (int p = 0; p < 4; ++p) {
      int i = t + 256 * p;  // 0..1023
      int cc = i >> 5, q = (i & 31) * 4;
      *(float4*)&md_s[cc * 128 + q] =
          *(const float4*)&Md[(size_t)(bb * CDIM + c0 + cc) * N + n0 + q];
      *(float4*)&x_s[cc * 128 + q] =
          *(const float4*)&x[(size_t)(bb * CDIM + c0 + cc) * N + n0 + q];
    }
    __syncthreads();
#pragma unroll 8
    for (int cc = 0; cc < 32; ++cc) {
      float4 a1 = *(const float4*)&w1_s[cc * 64 + ty4];
      float4 a2 = *(const float4*)&w2_s[cc * 64 + ty4];
      float4 b1a = *(const float4*)&md_s[cc * 128 + tx8];
      float4 b1b = *(const float4*)&md_s[cc * 128 + tx8 + 4];
      float4 b2a = *(const float4*)&x_s[cc * 128 + tx8];
      float4 b2b = *(const float4*)&x_s[cc * 128 + tx8 + 4];
      float a1v[4] = {a1.x, a1.y, a1.z, a1.w};
      float a2v[4] = {a2.x, a2.y, a2.z, a2.w};
      float b1v[8] = {b1a.x, b1a.y, b1a.z, b1a.w, b1b.x, b1b.y, b1b.z, b1b.w};
      float b2v[8] = {b2a.x, b2a.y, b2a.z, b2a.w, b2b.x, b2b.y, b2b.z, b2b.w};
#pragma unroll
      for (int i = 0; i < 4; ++i)
#pragma unroll
        for (int j = 0; j < 8; ++j)
          acc[i][j] += a1v[i] * b1v[j] + a2v[i] * b2v[j];
    }
  }

#pragma unroll
  for (int i = 0; i < 4; ++i) {
    int o = o0 + ty4 + i;
    float bv = bias[o];
    float4 r0 = make_float4(acc[i][0] + bv, acc[i][1] + bv, acc[i][2] + bv, acc[i][3] + bv);
    float4 r1 = make_float4(acc[i][4] + bv, acc[i][5] + bv, acc[i][6] + bv, acc[i][7] + bv);
    float* po = out + (size_t)(bb * O + o) * N + n0 + tx8;
    *(float4*)&po[0] = r0;
    *(float4*)&po[4] = r1;
  }
}

// ---------------------------------------------------------------------------
extern "C" void kernel_launch(void* const* d_in, const int* in_sizes, int n_in,
                              void* d_out, int out_size, void* d_ws, size_t ws_size,
                              hipStream_t stream) {
  const float* x = (const float*)d_in[0];     // (4,128,4096) fp32
  const float* W = (const float*)d_in[1];     // (256,256,1,1) fp32
  const float* bias = (const float*)d_in[2];  // (256,) fp32
  float* out = (float*)d_out;                 // (4,256,4096) fp32

  // workspace carve (16B-aligned)
  float* xx = (float*)d_ws;                                      // 64 KB
  int* idx = (int*)((char*)d_ws + 65536);                        // 640 KB
  float* Md = (float*)((char*)d_ws + 65536 + 655360);            // 8 MB
  float* pval = (float*)((char*)d_ws + 9109504);                 // 5.25 MB
  int* pidx = (int*)((char*)d_ws + 9109504 + 5242880);           // 5.25 MB

  xx_kernel<<<dim3(256), 256, 0, stream>>>(x, xx);
  topk_kernel<<<dim3(64, MSPLIT, 4), 256, 0, stream>>>(x, xx, pval, pidx);
  merge_kernel<<<dim3(64), 256, 0, stream>>>(pval, pidx, idx);
  gather_kernel<<<dim3(128, 4), 256, 0, stream>>>(x, idx, Md);
  out_kernel<<<dim3(32, 4, 4), 256, 0, stream>>>(Md, x, W, bias, out);
}

// Round 5
// 688.270 us; speedup vs baseline: 1.0408x; 1.0408x over previous
//
#include <hip/hip_runtime.h>

#define BDIM 4
#define CDIM 128
#define NDIM 4096
#define KSEL 10
#define MSPLIT 8
#define MT_PER (NDIM / MSPLIT / 128)  // 4 m-tiles of 128 per block

// ---------------------------------------------------------------------------
// Kernel A: xx[b][n] = sum_c x[b][c][n]^2
// ---------------------------------------------------------------------------
__global__ __launch_bounds__(256) void xx_kernel(const float* __restrict__ x,
                                                 float* __restrict__ xx) {
  int t = threadIdx.x;
  int nl = t >> 2;
  int part = t & 3;
  int g = blockIdx.x * 64 + nl;      // 0..B*N-1
  int b = g >> 12;
  int n = g & (NDIM - 1);
  const float* xp = x + (size_t)b * CDIM * NDIM + n;
  float s = 0.f;
  int c0 = part * 32;
#pragma unroll
  for (int i = 0; i < 32; ++i) {
    float v = xp[(size_t)(c0 + i) * NDIM];
    s += v * v;
  }
  s += __shfl_xor(s, 1, 4);
  s += __shfl_xor(s, 2, 4);
  if (part == 0) xx[g] = s;
}

// ---------------------------------------------------------------------------
// Kernel B: fused distance-GEMM + top-10, m-split 8 ways.
// Block = 64 rows x 512 cols (4 m-tiles of 128). 256 threads.
// GEMM: thread tile 4 rows x 8 cols (acc=32 regs, 32 FMA : 3 ds_read_b128/c).
//
// REGISTER-BUDGET CONTROL (R2-R4 post-mortem): the backend derives its
// occupancy target from LDS usage. At 25-34 KB LDS it targets >=4 waves/SIMD,
// caps VGPRs at/below the ~125-reg demand, and spills tv/ti/acc to scratch
// (R3: 729 MB scratch writes -> spill-BW-bound). At 75 KB (R1) it targeted
// 2 waves/SIMD and allocated 116 VGPRs, zero spill. So:
//   (a) LDS padded to 41984 B -> 3 blocks/CU -> target 3 waves/SIMD,
//       VGPR cap ~170 > demand -> no spill, still 12 waves/CU occupancy.
//   (b) amdgpu_waves_per_eu(2,4) -> allocator min-occupancy 2 waves/EU ->
//       hard budget 256 VGPRs, independent of the LDS heuristic.
// Emits per-(row,split) SORTED partial top-10 (val desc, idx asc).
// ---------------------------------------------------------------------------
__global__ __attribute__((amdgpu_waves_per_eu(2, 4))) __launch_bounds__(256)
void topk_kernel(const float* __restrict__ x,
                 const float* __restrict__ xxg,
                 float* __restrict__ pval,
                 int* __restrict__ pidx) {
  const int N = NDIM;
  int bb = blockIdx.z;
  int ms = blockIdx.y;
  int n0 = blockIdx.x * 64;
  int t = threadIdx.x;
  int tx = t & 15, ty = t >> 4;
  int tx4 = tx * 4, ty4 = ty * 4;

  __shared__ float smem[10496];  // 41984 B (8448+128 used; padded, see header)
  float* xn = smem;            // [32][64]   2048 f  (aliased by sc)
  float* xm = smem + 2048;     // [32][128]  4096 f  (aliased by sc)
  float* sc = smem;            // [64][132]  8448 f  (aliases xn+xm)
  float* xxs = smem + 8448;    // [128]

  const float* xb = x + (size_t)bb * CDIM * N;
  const float* xxb = xxg + (size_t)bb * N;

  // one private top-10 list per thread (static indexing only)
  float tv[KSEL];
  int ti[KSEL];
#pragma unroll
  for (int s = 0; s < KSEL; ++s) { tv[s] = -1e30f; ti[s] = 0x7fffffff; }
  float minv = -1e30f;
  int mini = 0x7fffffff;
  int minp = 0;

  // staging address precompute (linear float4 layout -> conflict-free)
  int xn_cc[2], xn_q[2], xm_cc[4], xm_q[4];
#pragma unroll
  for (int p = 0; p < 2; ++p) { int i4 = t + 256 * p; xn_cc[p] = i4 >> 4; xn_q[p] = (i4 & 15) * 4; }
#pragma unroll
  for (int p = 0; p < 4; ++p) { int i4 = t + 256 * p; xm_cc[p] = i4 >> 5; xm_q[p] = (i4 & 31) * 4; }

  int msbase = ms * (NDIM / MSPLIT);  // ms*512
  float4 pxn[2], pxm[4];
  auto issue = [&](int u) {  // u = mt*4+ch ; prefetch global->regs
    int m0u = msbase + (u >> 2) * 128;
    int c0u = (u & 3) * 32;
#pragma unroll
    for (int p = 0; p < 2; ++p)
      pxn[p] = *(const float4*)&xb[(size_t)(c0u + xn_cc[p]) * N + n0 + xn_q[p]];
#pragma unroll
    for (int p = 0; p < 4; ++p)
      pxm[p] = *(const float4*)&xb[(size_t)(c0u + xm_cc[p]) * N + m0u + xm_q[p]];
  };

  issue(0);
  const int NCHUNK = MT_PER * 4;  // 16

  for (int mt = 0; mt < MT_PER; ++mt) {
    int m0 = msbase + mt * 128;
    float acc[4][8];
#pragma unroll
    for (int i = 0; i < 4; ++i)
#pragma unroll
      for (int j = 0; j < 8; ++j) acc[i][j] = 0.f;

    for (int ch = 0; ch < 4; ++ch) {
      int u = mt * 4 + ch;
      __syncthreads();  // prior LDS consumers (prev chunk GEMM / prev mt scan)
#pragma unroll
      for (int p = 0; p < 2; ++p) *(float4*)&xn[xn_cc[p] * 64 + xn_q[p]] = pxn[p];
#pragma unroll
      for (int p = 0; p < 4; ++p) *(float4*)&xm[xm_cc[p] * 128 + xm_q[p]] = pxm[p];
      if (ch == 0 && t < 128) xxs[t] = xxb[m0 + t];
      __syncthreads();
      if (u + 1 < NCHUNK) issue(u + 1);  // overlap next stage with compute

#pragma unroll 8
      for (int cc = 0; cc < 32; ++cc) {
        // a: 4 distinct b128 addrs on distinct banks, broadcast over tx
        float4 a = *(const float4*)&xn[cc * 64 + ty4];
        // b: 16 distinct b128 addrs, 2 per 4-bank group -> free
        float4 b0 = *(const float4*)&xm[cc * 128 + tx4];
        float4 b1 = *(const float4*)&xm[cc * 128 + tx4 + 64];
        float av[4] = {a.x, a.y, a.z, a.w};
        float bv[8] = {b0.x, b0.y, b0.z, b0.w, b1.x, b1.y, b1.z, b1.w};
#pragma unroll
        for (int i = 0; i < 4; ++i)
#pragma unroll
          for (int j = 0; j < 8; ++j) acc[i][j] += av[i] * bv[j];
      }
    }

    // all xn/xm reads done; write scores over the aliased region
    __syncthreads();
    {
      float4 xq0 = *(const float4*)&xxs[tx4];
      float4 xq1 = *(const float4*)&xxs[tx4 + 64];
      float xv[8] = {xq0.x, xq0.y, xq0.z, xq0.w, xq1.x, xq1.y, xq1.z, xq1.w};
#pragma unroll
      for (int i = 0; i < 4; ++i) {
        int r = ty4 + i;
        float4 s0 = make_float4(2.f * acc[i][0] - xv[0], 2.f * acc[i][1] - xv[1],
                                2.f * acc[i][2] - xv[2], 2.f * acc[i][3] - xv[3]);
        float4 s1 = make_float4(2.f * acc[i][4] - xv[4], 2.f * acc[i][5] - xv[5],
                                2.f * acc[i][6] - xv[6], 2.f * acc[i][7] - xv[7]);
        *(float4*)&sc[r * 132 + tx4] = s0;
        *(float4*)&sc[r * 132 + tx4 + 64] = s1;
      }
    }
    __syncthreads();

    // scan: thread (rr = t>>2, q = t&3) takes cols == q (mod 4)
    // bank = (4*rr + q + 4*i) mod 32 -> exactly 2 lanes/bank = free
    {
      int rr = t >> 2, q = t & 3;
      const float* srow = &sc[rr * 132 + q];
      int gbase = m0 + q;
#pragma unroll 8
      for (int i = 0; i < 32; ++i) {
        float v = srow[4 * i];
        int gm = gbase + 4 * i;
        if (v > minv || (v == minv && gm < mini)) {
#pragma unroll
          for (int s = 0; s < KSEL; ++s)
            if (minp == s) { tv[s] = v; ti[s] = gm; }
          minv = tv[0]; mini = ti[0]; minp = 0;
#pragma unroll
          for (int s = 1; s < KSEL; ++s)
            if (tv[s] < minv || (tv[s] == minv && ti[s] > mini)) {
              minv = tv[s]; mini = ti[s]; minp = s;
            }
        }
      }
    }
    // next mt's first-chunk barrier protects sc until staging overwrites it
  }

  // ----- merge 4 partial lists per row -> sorted partial top-10 -----
  __syncthreads();
  {
    int rr = t >> 2, q = t & 3;
    float* mv = smem;                   // [64][40]
    int* mi = (int*)(smem + 2560);      // [64][40]
#pragma unroll
    for (int s = 0; s < KSEL; ++s) {
      mv[rr * 40 + q * 10 + s] = tv[s];
      mi[rr * 40 + q * 10 + s] = ti[s];
    }
  }
  __syncthreads();
  if (t < 64) {
    int row = t;
    float* mv = smem + row * 40;
    int* mi = (int*)(smem + 2560) + row * 40;
    size_t obase = ((size_t)(bb * MSPLIT + ms) * N + n0 + row) * KSEL;
    for (int s = 0; s < KSEL; ++s) {
      float bvv = -3e38f;
      int bi = 0x7fffffff, bp = 0;
      for (int j = 0; j < 40; ++j) {
        float v = mv[j];
        int id = mi[j];
        if (v > bvv || (v == bvv && id < bi)) { bvv = v; bi = id; bp = j; }
      }
      mv[bp] = -3e38f;
      pval[obase + s] = bvv;
      pidx[obase + s] = bi;
    }
  }
}

// ---------------------------------------------------------------------------
// Kernel B2: merge the 8 sorted split-partials per row -> final top-10 idx
// ---------------------------------------------------------------------------
__global__ __launch_bounds__(256) void merge_kernel(const float* __restrict__ pval,
                                                    const int* __restrict__ pidx,
                                                    int* __restrict__ idxout) {
  int g = blockIdx.x * 256 + threadIdx.x;  // 0..B*N-1
  int b = g >> 12;
  int n = g & (NDIM - 1);
  int hp[MSPLIT];
#pragma unroll
  for (int q = 0; q < MSPLIT; ++q) hp[q] = 0;
  int* op = idxout + ((size_t)b * NDIM + n) * KSEL;
  for (int s = 0; s < KSEL; ++s) {
    float bv = -3e38f; int bi = 0x7fffffff; int bq = 0;
#pragma unroll
    for (int q = 0; q < MSPLIT; ++q) {
      if (hp[q] < KSEL) {
        size_t o = ((size_t)(b * MSPLIT + q) * NDIM + n) * KSEL + hp[q];
        float v = pval[o];
        int id = pidx[o];
        if (v > bv || (v == bv && id < bi)) { bv = v; bi = id; bq = q; }
      }
    }
#pragma unroll
    for (int q = 0; q < MSPLIT; ++q)
      if (bq == q) hp[q]++;
    op[s] = bi;
  }
}

// ---------------------------------------------------------------------------
// Kernel C: Md[b][c][n] = mean_k x[b][c][idx[b][n][k]] - x[b][c][n]
// ---------------------------------------------------------------------------
__global__ __launch_bounds__(256) void gather_kernel(const float* __restrict__ x,
                                                     const int* __restrict__ idxg,
                                                     float* __restrict__ Md) {
  const int N = NDIM;
  int bb = blockIdx.y, c = blockIdx.x;
  __shared__ float row_s[NDIM];
  const float* rowg = x + (size_t)(bb * CDIM + c) * N;
  int t = threadIdx.x;
#pragma unroll
  for (int p = 0; p < 4; ++p) {
    int i4 = t + 256 * p;
    *(float4*)&row_s[i4 * 4] = *(const float4*)&rowg[i4 * 4];
  }
  __syncthreads();
  float* outp = Md + (size_t)(bb * CDIM + c) * N;
  const int* ib = idxg + (size_t)bb * N * KSEL;
  for (int p = 0; p < 16; ++p) {
    int n = t + 256 * p;
    const int* ip = ib + (size_t)n * KSEL;
    float s = 0.f;
#pragma unroll
    for (int k = 0; k < KSEL; ++k) s += row_s[ip[k]];
    outp[n] = s * 0.1f - row_s[n];
  }
}

// ---------------------------------------------------------------------------
// Kernel D: out[b][o][n] = sum_c W[o][c]*Md[b][c][n] + W[o][128+c]*x[b][c][n] + b[o]
// ---------------------------------------------------------------------------
__global__ __launch_bounds__(256) void out_kernel(const float* __restrict__ Md,
                                                  const float* __restrict__ x,
                                                  const float* __restrict__ W,
                                                  const float* __restrict__ bias,
                                                  float* __restrict__ out) {
  const int N = NDIM, O = 256;
  int bb = blockIdx.z;
  int o0 = blockIdx.y * 64;
  int n0 = blockIdx.x * 128;
  int t = threadIdx.x;
  int tx = t & 15, ty = t >> 4;
  int tx8 = tx * 8, ty4 = ty * 4;

  __shared__ float w1_s[32 * 64];    // [cc][o]
  __shared__ float w2_s[32 * 64];
  __shared__ float md_s[32 * 128];   // [cc][n]
  __shared__ float x_s[32 * 128];

  float acc[4][8];
#pragma unroll
  for (int i = 0; i < 4; ++i)
#pragma unroll
    for (int j = 0; j < 8; ++j) acc[i][j] = 0.f;

  for (int ch = 0; ch < 4; ++ch) {
    int c0 = ch * 32;
    __syncthreads();
#pragma unroll
    for (int p = 0; p < 2; ++p) {
      int i = t + 256 * p;  // 0..511
      int oo = i >> 3, q = i & 7;
      float4 v1 = *(const float4*)&W[(size_t)(o0 + oo) * 256 + c0 + q * 4];
      float4 v2 = *(const float4*)&W[(size_t)(o0 + oo) * 256 + 128 + c0 + q * 4];
      w1_s[(q * 4 + 0) * 64 + oo] = v1.x;
      w1_s[(q * 4 + 1) * 64 + oo] = v1.y;
      w1_s[(q * 4 + 2) * 64 + oo] = v1.z;
      w1_s[(q * 4 + 3) * 64 + oo] = v1.w;
      w2_s[(q * 4 + 0) * 64 + oo] = v2.x;
      w2_s[(q * 4 + 1) * 64 + oo] = v2.y;
      w2_s[(q * 4 + 2) * 64 + oo] = v2.z;
      w2_s[(q * 4 + 3) * 64 + oo] = v2.w;
    }
#pragma unroll
    for (int p = 0; p < 4; ++p) {
      int i = t + 256 * p;  // 0..1023
      int cc = i >> 5, q = (i & 31) * 4;
      *(float4*)&md_s[cc * 128 + q] =
          *(const float4*)&Md[(size_t)(bb * CDIM + c0 + cc) * N + n0 + q];
      *(float4*)&x_s[cc * 128 + q] =
          *(const float4*)&x[(size_t)(bb * CDIM + c0 + cc) * N + n0 + q];
    }
    __syncthreads();
#pragma unroll 8
    for (int cc = 0; cc < 32; ++cc) {
      float4 a1 = *(const float4*)&w1_s[cc * 64 + ty4];
      float4 a2 = *(const float4*)&w2_s[cc * 64 + ty4];
      float4 b1a = *(const float4*)&md_s[cc * 128 + tx8];
      float4 b1b = *(const float4*)&md_s[cc * 128 + tx8 + 4];
      float4 b2a = *(const float4*)&x_s[cc * 128 + tx8];
      float4 b2b = *(const float4*)&x_s[cc * 128 + tx8 + 4];
      float a1v[4] = {a1.x, a1.y, a1.z, a1.w};
      float a2v[4] = {a2.x, a2.y, a2.z, a2.w};
      float b1v[8] = {b1a.x, b1a.y, b1a.z, b1a.w, b1b.x, b1b.y, b1b.z, b1b.w};
      float b2v[8] = {b2a.x, b2a.y, b2a.z, b2a.w, b2b.x, b2b.y, b2b.z, b2b.w};
#pragma unroll
      for (int i = 0; i < 4; ++i)
#pragma unroll
        for (int j = 0; j < 8; ++j)
          acc[i][j] += a1v[i] * b1v[j] + a2v[i] * b2v[j];
    }
  }

#pragma unroll
  for (int i = 0; i < 4; ++i) {
    int o = o0 + ty4 + i;
    float bv = bias[o];
    float4 r0 = make_float4(acc[i][0] + bv, acc[i][1] + bv, acc[i][2] + bv, acc[i][3] + bv);
    float4 r1 = make_float4(acc[i][4] + bv, acc[i][5] + bv, acc[i][6] + bv, acc[i][7] + bv);
    float* po = out + (size_t)(bb * O + o) * N + n0 + tx8;
    *(float4*)&po[0] = r0;
    *(float4*)&po[4] = r1;
  }
}

// ---------------------------------------------------------------------------
extern "C" void kernel_launch(void* const* d_in, const int* in_sizes, int n_in,
                              void* d_out, int out_size, void* d_ws, size_t ws_size,
                              hipStream_t stream) {
  const float* x = (const float*)d_in[0];     // (4,128,4096) fp32
  const float* W = (const float*)d_in[1];     // (256,256,1,1) fp32
  const float* bias = (const float*)d_in[2];  // (256,) fp32
  float* out = (float*)d_out;                 // (4,256,4096) fp32

  // workspace carve (16B-aligned)
  float* xx = (float*)d_ws;                                      // 64 KB
  int* idx = (int*)((char*)d_ws + 65536);                        // 640 KB
  float* Md = (float*)((char*)d_ws + 65536 + 655360);            // 8 MB
  float* pval = (float*)((char*)d_ws + 9109504);                 // 5.25 MB
  int* pidx = (int*)((char*)d_ws + 9109504 + 5242880);           // 5.25 MB

  xx_kernel<<<dim3(256), 256, 0, stream>>>(x, xx);
  topk_kernel<<<dim3(64, MSPLIT, 4), 256, 0, stream>>>(x, xx, pval, pidx);
  merge_kernel<<<dim3(64), 256, 0, stream>>>(pval, pidx, idx);
  gather_kernel<<<dim3(128, 4), 256, 0, stream>>>(x, idx, Md);
  out_kernel<<<dim3(32, 4, 4), 256, 0, stream>>>(Md, x, W, bias, out);
}

// Round 6
// 568.152 us; speedup vs baseline: 1.2609x; 1.2114x over previous
//
#include <hip/hip_runtime.h>
#include <stdint.h>

#define BDIM 4
#define CDIM 128
#define NDIM 4096
#define KSEL 10

typedef unsigned long long ull;

// CK-style global->LDS direct copy (16 B/lane). LDS generic ptr low 32 bits
// are the LDS offset on gfx9+; global generic == as(1) numerically.
__device__ __forceinline__ void async_cp16(void* lds, const void* g) {
  auto* gp = (const __attribute__((address_space(1))) unsigned int*)(uintptr_t)g;
  auto* lp = (__attribute__((address_space(3))) unsigned int*)(unsigned int)(uintptr_t)lds;
  __builtin_amdgcn_global_load_lds(gp, lp, 16, 0, 0);
}

// ---------------------------------------------------------------------------
// Kernel A: xx[b][n] = sum_c x[b][c][n]^2
// ---------------------------------------------------------------------------
__global__ __launch_bounds__(256) void xx_kernel(const float* __restrict__ x,
                                                 float* __restrict__ xx) {
  int t = threadIdx.x;
  int nl = t >> 2;
  int part = t & 3;
  int g = blockIdx.x * 64 + nl;      // 0..B*N-1
  int b = g >> 12;
  int n = g & (NDIM - 1);
  const float* xp = x + (size_t)b * CDIM * NDIM + n;
  float s = 0.f;
  int c0 = part * 32;
#pragma unroll
  for (int i = 0; i < 32; ++i) {
    float v = xp[(size_t)(c0 + i) * NDIM];
    s += v * v;
  }
  s += __shfl_xor(s, 1, 4);
  s += __shfl_xor(s, 2, 4);
  if (part == 0) xx[g] = s;
}

// ---------------------------------------------------------------------------
// Kernel S: pure score GEMM. sc[lr][m] = 2*sum_c x[c][n]x[c][m] - xx[m]
// Block 128n x 128m, 256 threads, thread tile 8x8 (64 acc = 1.0 B LDS/FMA,
// the CU balance point). C chunked by 32, staged with global_load_lds w=16.
// No top-k state -> VGPR demand ~100, below any allocator cap. LDS padded
// to 40960 B so the occupancy heuristic targets <=4 waves/EU (cap 128).
// ---------------------------------------------------------------------------
__global__ __launch_bounds__(256) void score_kernel(const float* __restrict__ x,
                                                    const float* __restrict__ xxg,
                                                    float* __restrict__ sc,
                                                    int bb, int n_off) {
  const int N = NDIM;
  int n0 = n_off + blockIdx.x * 128;
  int m0 = blockIdx.y * 128;
  int t = threadIdx.x;
  int tx = t & 15, ty = t >> 4;
  int tx4 = tx * 4, ty4 = ty * 4;

  __shared__ float smem[10240];      // 40960 B (8192 used + pad, see header)
  float* xn_s = smem;                // [32][128]
  float* xm_s = smem + 4096;         // [32][128]

  const float* xb = x + (size_t)bb * CDIM * N;

  float acc[8][8];
#pragma unroll
  for (int i = 0; i < 8; ++i)
#pragma unroll
    for (int j = 0; j < 8; ++j) acc[i][j] = 0.f;

  int scc = t >> 5;                  // staging row base (0..7)
  int sq = (t & 31) * 4;             // staging col (float)

  for (int ch = 0; ch < 4; ++ch) {
    int c0 = ch * 32;
    __syncthreads();  // previous chunk's readers done
#pragma unroll
    for (int p = 0; p < 4; ++p) {
      int i4 = t + 256 * p;
      async_cp16(&xn_s[i4 * 4], &xb[(size_t)(c0 + scc + 8 * p) * N + n0 + sq]);
    }
#pragma unroll
    for (int p = 0; p < 4; ++p) {
      int i4 = t + 256 * p;
      async_cp16(&xm_s[i4 * 4], &xb[(size_t)(c0 + scc + 8 * p) * N + m0 + sq]);
    }
    __syncthreads();  // vmcnt(0) drain -> LDS valid

#pragma unroll 4
    for (int cc = 0; cc < 32; ++cc) {
      // a: 4 distinct b128 addrs/wave, 16-lane broadcast -> free
      float4 a0 = *(const float4*)&xn_s[cc * 128 + ty4];
      float4 a1 = *(const float4*)&xn_s[cc * 128 + ty4 + 64];
      // b: 16 distinct b128 addrs, 2 lanes/bank -> free
      float4 b0 = *(const float4*)&xm_s[cc * 128 + tx4];
      float4 b1 = *(const float4*)&xm_s[cc * 128 + tx4 + 64];
      float av[8] = {a0.x, a0.y, a0.z, a0.w, a1.x, a1.y, a1.z, a1.w};
      float bv[8] = {b0.x, b0.y, b0.z, b0.w, b1.x, b1.y, b1.z, b1.w};
#pragma unroll
      for (int i = 0; i < 8; ++i)
#pragma unroll
        for (int j = 0; j < 8; ++j) acc[i][j] += av[i] * bv[j];
    }
  }

  // epilogue: score = 2*dot - xx[m]; xx read direct from global (L1/L2-hot)
  const float* xxb = xxg + (size_t)bb * N;
  float4 w0 = *(const float4*)&xxb[m0 + tx4];
  float4 w1 = *(const float4*)&xxb[m0 + tx4 + 64];
  float wv[8] = {w0.x, w0.y, w0.z, w0.w, w1.x, w1.y, w1.z, w1.w};
#pragma unroll
  for (int i = 0; i < 8; ++i) {
    int lr = blockIdx.x * 128 + ty4 + (i & 3) + (i >> 2) * 64;
    float* po = sc + (size_t)lr * N + m0;
    *(float4*)&po[tx4] =
        make_float4(2.f * acc[i][0] - wv[0], 2.f * acc[i][1] - wv[1],
                    2.f * acc[i][2] - wv[2], 2.f * acc[i][3] - wv[3]);
    *(float4*)&po[tx4 + 64] =
        make_float4(2.f * acc[i][4] - wv[4], 2.f * acc[i][5] - wv[5],
                    2.f * acc[i][6] - wv[6], 2.f * acc[i][7] - wv[7]);
  }
}

// ---------------------------------------------------------------------------
// Kernel T: top-10 scan. One wave per row; lane l scans m = 64j + l.
// Keys packed u64: mono(v)<<32 | (4095 - m)  ->  (val desc, idx asc) exact.
// Per-lane top-10 in regs (20 VGPR), butterfly-shuffle tournament merge.
// ---------------------------------------------------------------------------
__global__ __launch_bounds__(256) void scan_kernel(const float* __restrict__ sc,
                                                   int* __restrict__ idxout,
                                                   int bb, int n_off) {
  int t = threadIdx.x;
  int lane = t & 63;
  int w = t >> 6;
  int lrow = blockIdx.x * 4 + w;
  int row = n_off + lrow;
  const float* srow = sc + (size_t)lrow * NDIM;

  ull kv[KSEL];
#pragma unroll
  for (int s = 0; s < KSEL; ++s) kv[s] = 0ull;
  ull minkv = 0ull;
  int minp = 0;
  unsigned mbase = (unsigned)(4095 - lane);

#pragma unroll 4
  for (int j = 0; j < 64; ++j) {
    float v = srow[(j << 6) + lane];
    unsigned u = __float_as_uint(v);
    unsigned mono = u ^ ((unsigned)(((int)u) >> 31) | 0x80000000u);
    ull key = ((ull)mono << 32) | (ull)(mbase - (unsigned)(j << 6));
    if (key > minkv) {
#pragma unroll
      for (int s = 0; s < KSEL; ++s)
        if (minp == s) kv[s] = key;
      minkv = kv[0]; minp = 0;
#pragma unroll
      for (int s = 1; s < KSEL; ++s)
        if (kv[s] < minkv) { minkv = kv[s]; minp = s; }
    }
  }

  // sort desc (static network)
#pragma unroll
  for (int a = 0; a < KSEL - 1; ++a)
#pragma unroll
    for (int b2 = 0; b2 < KSEL - 1 - a; ++b2)
      if (kv[b2] < kv[b2 + 1]) { ull tmp = kv[b2]; kv[b2] = kv[b2 + 1]; kv[b2 + 1] = tmp; }

  // tournament: 10 rounds of wave-max over heads; winner shifts down
  int my = 0;
  for (int s = 0; s < KSEL; ++s) {
    ull mx = kv[0];
#pragma unroll
    for (int off = 1; off < 64; off <<= 1) {
      ull o = __shfl_xor(mx, off);
      if (o > mx) mx = o;
    }
    if (kv[0] == mx) {  // exactly one lane (keys unique)
#pragma unroll
      for (int i = 0; i < KSEL - 1; ++i) kv[i] = kv[i + 1];
      kv[KSEL - 1] = 0ull;
    }
    if (lane == s) my = 4095 - (int)(unsigned)(mx & 0xFFFFFFFFull);
  }
  if (lane < KSEL)
    idxout[((size_t)bb * NDIM + row) * KSEL + lane] = my;
}

// ---------------------------------------------------------------------------
// Kernel C: Md[b][c][n] = mean_k x[b][c][idx[b][n][k]] - x[b][c][n]
// ---------------------------------------------------------------------------
__global__ __launch_bounds__(256) void gather_kernel(const float* __restrict__ x,
                                                     const int* __restrict__ idxg,
                                                     float* __restrict__ Md) {
  const int N = NDIM;
  int bb = blockIdx.y, c = blockIdx.x;
  __shared__ float row_s[NDIM];
  const float* rowg = x + (size_t)(bb * CDIM + c) * N;
  int t = threadIdx.x;
#pragma unroll
  for (int p = 0; p < 4; ++p) {
    int i4 = t + 256 * p;
    *(float4*)&row_s[i4 * 4] = *(const float4*)&rowg[i4 * 4];
  }
  __syncthreads();
  float* outp = Md + (size_t)(bb * CDIM + c) * N;
  const int* ib = idxg + (size_t)bb * N * KSEL;
  for (int p = 0; p < 16; ++p) {
    int n = t + 256 * p;
    const int* ip = ib + (size_t)n * KSEL;
    float s = 0.f;
#pragma unroll
    for (int k = 0; k < KSEL; ++k) s += row_s[ip[k]];
    outp[n] = s * 0.1f - row_s[n];
  }
}

// ---------------------------------------------------------------------------
// Kernel D: out[b][o][n] = sum_c W[o][c]*Md[b][c][n] + W[o][128+c]*x[b][c][n] + b[o]
// ---------------------------------------------------------------------------
__global__ __launch_bounds__(256) void out_kernel(const float* __restrict__ Md,
                                                  const float* __restrict__ x,
                                                  const float* __restrict__ W,
                                                  const float* __restrict__ bias,
                                                  float* __restrict__ out) {
  const int N = NDIM, O = 256;
  int bb = blockIdx.z;
  int o0 = blockIdx.y * 64;
  int n0 = blockIdx.x * 128;
  int t = threadIdx.x;
  int tx = t & 15, ty = t >> 4;
  int tx8 = tx * 8, ty4 = ty * 4;

  __shared__ float w1_s[32 * 64];    // [cc][o]
  __shared__ float w2_s[32 * 64];
  __shared__ float md_s[32 * 128];   // [cc][n]
  __shared__ float x_s[32 * 128];

  float acc[4][8];
#pragma unroll
  for (int i = 0; i < 4; ++i)
#pragma unroll
    for (int j = 0; j < 8; ++j) acc[i][j] = 0.f;

  for (int ch = 0; ch < 4; ++ch) {
    int c0 = ch * 32;
    __syncthreads();
#pragma unroll
    for (int p = 0; p < 2; ++p) {
      int i = t + 256 * p;  // 0..511
      int oo = i >> 3, q = i & 7;
      float4 v1 = *(const float4*)&W[(size_t)(o0 + oo) * 256 + c0 + q * 4];
      float4 v2 = *(const float4*)&W[(size_t)(o0 + oo) * 256 + 128 + c0 + q * 4];
      w1_s[(q * 4 + 0) * 64 + oo] = v1.x;
      w1_s[(q * 4 + 1) * 64 + oo] = v1.y;
      w1_s[(q * 4 + 2) * 64 + oo] = v1.z;
      w1_s[(q * 4 + 3) * 64 + oo] = v1.w;
      w2_s[(q * 4 + 0) * 64 + oo] = v2.x;
      w2_s[(q * 4 + 1) * 64 + oo] = v2.y;
      w2_s[(q * 4 + 2) * 64 + oo] = v2.z;
      w2_s[(q * 4 + 3) * 64 + oo] = v2.w;
    }
#pragma unroll
    for (int p = 0; p < 4; ++p) {
      int i = t + 256 * p;  // 0..1023
      int cc = i >> 5, q = (i & 31) * 4;
      *(float4*)&md_s[cc * 128 + q] =
          *(const float4*)&Md[(size_t)(bb * CDIM + c0 + cc) * N + n0 + q];
      *(float4*)&x_s[cc * 128 + q] =
          *(const float4*)&x[(size_t)(bb * CDIM + c0 + cc) * N + n0 + q];
    }
    __syncthreads();
#pragma unroll 8
    for (int cc = 0; cc < 32; ++cc) {
      float4 a1 = *(const float4*)&w1_s[cc * 64 + ty4];
      float4 a2 = *(const float4*)&w2_s[cc * 64 + ty4];
      float4 b1a = *(const float4*)&md_s[cc * 128 + tx8];
      float4 b1b = *(const float4*)&md_s[cc * 128 + tx8 + 4];
      float4 b2a = *(const float4*)&x_s[cc * 128 + tx8];
      float4 b2b = *(const float4*)&x_s[cc * 128 + tx8 + 4];
      float a1v[4] = {a1.x, a1.y, a1.z, a1.w};
      float a2v[4] = {a2.x, a2.y, a2.z, a2.w};
      float b1v[8] = {b1a.x, b1a.y, b1a.z, b1a.w, b1b.x, b1b.y, b1b.z, b1b.w};
      float b2v[8] = {b2a.x, b2a.y, b2a.z, b2a.w, b2b.x, b2b.y, b2b.z, b2b.w};
#pragma unroll
      for (int i = 0; i < 4; ++i)
#pragma unroll
        for (int j = 0; j < 8; ++j)
          acc[i][j] += a1v[i] * b1v[j] + a2v[i] * b2v[j];
    }
  }

#pragma unroll
  for (int i = 0; i < 4; ++i) {
    int o = o0 + ty4 + i;
    float bv = bias[o];
    float4 r0 = make_float4(acc[i][0] + bv, acc[i][1] + bv, acc[i][2] + bv, acc[i][3] + bv);
    float4 r1 = make_float4(acc[i][4] + bv, acc[i][5] + bv, acc[i][6] + bv, acc[i][7] + bv);
    float* po = out + (size_t)(bb * O + o) * N + n0 + tx8;
    *(float4*)&po[0] = r0;
    *(float4*)&po[4] = r1;
  }
}

// ---------------------------------------------------------------------------
extern "C" void kernel_launch(void* const* d_in, const int* in_sizes, int n_in,
                              void* d_out, int out_size, void* d_ws, size_t ws_size,
                              hipStream_t stream) {
  const float* x = (const float*)d_in[0];     // (4,128,4096) fp32
  const float* W = (const float*)d_in[1];     // (256,256,1,1) fp32
  const float* bias = (const float*)d_in[2];  // (256,) fp32
  float* out = (float*)d_out;                 // (4,256,4096) fp32

  // workspace carve (16B-aligned): xx 64K | idx 640K | Md 8M | sc (chunked)
  float* xx = (float*)d_ws;
  int* idx = (int*)((char*)d_ws + 65536);
  float* Md = (float*)((char*)d_ws + 65536 + 655360);
  const size_t fixed = 9109504;
  float* sc = (float*)((char*)d_ws + fixed);

  // sc row-chunk: largest power-of-2 rows R with R*4096*4 fitting in scratch
  int R = 4096;
  while ((size_t)R * NDIM * 4 + fixed > ws_size && R > 128) R >>= 1;

  xx_kernel<<<dim3(256), 256, 0, stream>>>(x, xx);
  for (int b = 0; b < BDIM; ++b) {
    for (int off = 0; off < NDIM; off += R) {
      score_kernel<<<dim3(R / 128, 32), 256, 0, stream>>>(x, xx, sc, b, off);
      scan_kernel<<<dim3(R / 4), 256, 0, stream>>>(sc, idx, b, off);
    }
  }
  gather_kernel<<<dim3(128, 4), 256, 0, stream>>>(x, idx, Md);
  out_kernel<<<dim3(32, 4, 4), 256, 0, stream>>>(Md, x, W, bias, out);
}

// Round 7
// 466.406 us; speedup vs baseline: 1.5359x; 1.2181x over previous
//
#include <hip/hip_runtime.h>
#include <stdint.h>

#define BDIM 4
#define CDIM 128
#define NDIM 4096
#define KSEL 10

typedef unsigned long long ull;

// CK-style global->LDS direct copy (16 B/lane). LDS generic ptr low 32 bits
// are the LDS offset on gfx9+; global generic == as(1) numerically.
__device__ __forceinline__ void async_cp16(void* lds, const void* g) {
  auto* gp = (const __attribute__((address_space(1))) unsigned int*)(uintptr_t)g;
  auto* lp = (__attribute__((address_space(3))) unsigned int*)(unsigned int)(uintptr_t)lds;
  __builtin_amdgcn_global_load_lds(gp, lp, 16, 0, 0);
}

// ---------------------------------------------------------------------------
// Kernel A: xx[b][n] = sum_c x[b][c][n]^2
// ---------------------------------------------------------------------------
__global__ __launch_bounds__(256) void xx_kernel(const float* __restrict__ x,
                                                 float* __restrict__ xx) {
  int t = threadIdx.x;
  int nl = t >> 2;
  int part = t & 3;
  int g = blockIdx.x * 64 + nl;      // 0..B*N-1
  int b = g >> 12;
  int n = g & (NDIM - 1);
  const float* xp = x + (size_t)b * CDIM * NDIM + n;
  float s = 0.f;
  int c0 = part * 32;
#pragma unroll
  for (int i = 0; i < 32; ++i) {
    float v = xp[(size_t)(c0 + i) * NDIM];
    s += v * v;
  }
  s += __shfl_xor(s, 1, 4);
  s += __shfl_xor(s, 2, 4);
  if (part == 0) xx[g] = s;
}

// ---------------------------------------------------------------------------
// Kernel S: pure score GEMM. sc[lr][m] = 2*sum_c x[c][n]x[c][m] - xx[m]
// Block 128n x 128m, 256 threads, thread tile 8x8. Unchanged from R6.
// ---------------------------------------------------------------------------
__global__ __launch_bounds__(256) void score_kernel(const float* __restrict__ x,
                                                    const float* __restrict__ xxg,
                                                    float* __restrict__ sc,
                                                    int bb, int n_off) {
  const int N = NDIM;
  int n0 = n_off + blockIdx.x * 128;
  int m0 = blockIdx.y * 128;
  int t = threadIdx.x;
  int tx = t & 15, ty = t >> 4;
  int tx4 = tx * 4, ty4 = ty * 4;

  __shared__ float smem[10240];      // 40960 B (8192 used + pad; see R5 notes)
  float* xn_s = smem;                // [32][128]
  float* xm_s = smem + 4096;         // [32][128]

  const float* xb = x + (size_t)bb * CDIM * N;

  float acc[8][8];
#pragma unroll
  for (int i = 0; i < 8; ++i)
#pragma unroll
    for (int j = 0; j < 8; ++j) acc[i][j] = 0.f;

  int scc = t >> 5;                  // staging row base (0..7)
  int sq = (t & 31) * 4;             // staging col (float)

  for (int ch = 0; ch < 4; ++ch) {
    int c0 = ch * 32;
    __syncthreads();  // previous chunk's readers done
#pragma unroll
    for (int p = 0; p < 4; ++p) {
      int i4 = t + 256 * p;
      async_cp16(&xn_s[i4 * 4], &xb[(size_t)(c0 + scc + 8 * p) * N + n0 + sq]);
    }
#pragma unroll
    for (int p = 0; p < 4; ++p) {
      int i4 = t + 256 * p;
      async_cp16(&xm_s[i4 * 4], &xb[(size_t)(c0 + scc + 8 * p) * N + m0 + sq]);
    }
    __syncthreads();  // vmcnt(0) drain -> LDS valid

#pragma unroll 4
    for (int cc = 0; cc < 32; ++cc) {
      float4 a0 = *(const float4*)&xn_s[cc * 128 + ty4];
      float4 a1 = *(const float4*)&xn_s[cc * 128 + ty4 + 64];
      float4 b0 = *(const float4*)&xm_s[cc * 128 + tx4];
      float4 b1 = *(const float4*)&xm_s[cc * 128 + tx4 + 64];
      float av[8] = {a0.x, a0.y, a0.z, a0.w, a1.x, a1.y, a1.z, a1.w};
      float bv[8] = {b0.x, b0.y, b0.z, b0.w, b1.x, b1.y, b1.z, b1.w};
#pragma unroll
      for (int i = 0; i < 8; ++i)
#pragma unroll
        for (int j = 0; j < 8; ++j) acc[i][j] += av[i] * bv[j];
    }
  }

  const float* xxb = xxg + (size_t)bb * N;
  float4 w0 = *(const float4*)&xxb[m0 + tx4];
  float4 w1 = *(const float4*)&xxb[m0 + tx4 + 64];
  float wv[8] = {w0.x, w0.y, w0.z, w0.w, w1.x, w1.y, w1.z, w1.w};
#pragma unroll
  for (int i = 0; i < 8; ++i) {
    int lr = blockIdx.x * 128 + ty4 + (i & 3) + (i >> 2) * 64;
    float* po = sc + (size_t)lr * N + m0;
    *(float4*)&po[tx4] =
        make_float4(2.f * acc[i][0] - wv[0], 2.f * acc[i][1] - wv[1],
                    2.f * acc[i][2] - wv[2], 2.f * acc[i][3] - wv[3]);
    *(float4*)&po[tx4 + 64] =
        make_float4(2.f * acc[i][4] - wv[4], 2.f * acc[i][5] - wv[5],
                    2.f * acc[i][6] - wv[6], 2.f * acc[i][7] - wv[7]);
  }
}

// ---------------------------------------------------------------------------
// Kernel T: top-10 scan, branchless top-2 + 10 argmax rounds.
// One wave per row; lane reads uint4 j4 in [0,16): m = j4*256 + lane*4 + e.
// Key u64 = mono(v)<<32 | (4095-m)  -> (val desc, idx asc) exact, key>0 always.
// Phase A: per-lane sorted top-2 (k1>=k2), fully branchless (~12 VALU/elem,
//   no wave-divergent update block — R6's 50-op masked insert ran every iter).
// Phase B: 10 rounds of wave u64-max. Winner promotes k2; if empty, rescans
//   its segment from global (L2-hot) for keys STRICTLY below the extracted
//   key — exact since extraction order is globally descending. Rare (~0.7/row).
// ---------------------------------------------------------------------------
__global__ __launch_bounds__(256) void scan_kernel(const float* __restrict__ sc,
                                                   int* __restrict__ idxout,
                                                   int bb, int n_off) {
  int t = threadIdx.x;
  int lane = t & 63;
  int w = t >> 6;
  int lrow = blockIdx.x * 4 + w;
  int row = n_off + lrow;
  const uint4* srow = (const uint4*)(sc + (size_t)lrow * NDIM);

  unsigned A0 = 4095u - (unsigned)(lane * 4);
  ull k1 = 0ull, k2 = 0ull;

#pragma unroll 4
  for (int j4 = 0; j4 < 16; ++j4) {
    uint4 q = srow[j4 * 64 + lane];
    unsigned vv[4] = {q.x, q.y, q.z, q.w};
#pragma unroll
    for (int e = 0; e < 4; ++e) {
      unsigned u = vv[e];
      unsigned mono = u ^ ((unsigned)(((int)u) >> 31) | 0x80000000u);
      ull key = ((ull)mono << 32) | (ull)(A0 - (unsigned)e - (unsigned)(j4 << 8));
      ull lo = k1 < key ? k1 : key;   // min(k1, key)   [old k1]
      k1 = k1 < key ? key : k1;      // max(k1, key)
      k2 = k2 < lo ? lo : k2;        // max(k2, lo)
    }
  }

  unsigned my = 0;
  for (int s = 0; s < KSEL; ++s) {
    ull mx = k1;
#pragma unroll
    for (int off = 1; off < 64; off <<= 1) {
      ull o = __shfl_xor(mx, off);
      if (o > mx) mx = o;
    }
    if (k1 == mx) {  // unique winner (keys unique, >0)
      if (k2 != 0ull) {
        k1 = k2;
        k2 = 0ull;
      } else {
        // rescan my segment for keys strictly below mx (rare, L2-hot)
        ull r1 = 0ull, r2 = 0ull;
        for (int j4 = 0; j4 < 16; ++j4) {
          uint4 q = srow[j4 * 64 + lane];
          unsigned vv[4] = {q.x, q.y, q.z, q.w};
#pragma unroll
          for (int e = 0; e < 4; ++e) {
            unsigned u = vv[e];
            unsigned mono = u ^ ((unsigned)(((int)u) >> 31) | 0x80000000u);
            ull key = ((ull)mono << 32) | (ull)(A0 - (unsigned)e - (unsigned)(j4 << 8));
            if (key < mx) {
              ull lo = r1 < key ? r1 : key;
              r1 = r1 < key ? key : r1;
              r2 = r2 < lo ? lo : r2;
            }
          }
        }
        k1 = r1;
        k2 = r2;
      }
    }
    if (lane == s) my = 4095u - (unsigned)(mx & 0xFFFFFFFFull);
  }
  if (lane < KSEL)
    idxout[((size_t)bb * NDIM + row) * KSEL + lane] = (int)my;
}

// ---------------------------------------------------------------------------
// Kernel C: Md[b][c][n] = mean_k x[b][c][idx[b][n][k]] - x[b][c][n]
// ---------------------------------------------------------------------------
__global__ __launch_bounds__(256) void gather_kernel(const float* __restrict__ x,
                                                     const int* __restrict__ idxg,
                                                     float* __restrict__ Md) {
  const int N = NDIM;
  int bb = blockIdx.y, c = blockIdx.x;
  __shared__ float row_s[NDIM];
  const float* rowg = x + (size_t)(bb * CDIM + c) * N;
  int t = threadIdx.x;
#pragma unroll
  for (int p = 0; p < 4; ++p) {
    int i4 = t + 256 * p;
    *(float4*)&row_s[i4 * 4] = *(const float4*)&rowg[i4 * 4];
  }
  __syncthreads();
  float* outp = Md + (size_t)(bb * CDIM + c) * N;
  const int* ib = idxg + (size_t)bb * N * KSEL;
  for (int p = 0; p < 16; ++p) {
    int n = t + 256 * p;
    const int* ip = ib + (size_t)n * KSEL;
    float s = 0.f;
#pragma unroll
    for (int k = 0; k < KSEL; ++k) s += row_s[ip[k]];
    outp[n] = s * 0.1f - row_s[n];
  }
}

// ---------------------------------------------------------------------------
// Kernel D: out[b][o][n] = sum_c W[o][c]*Md[b][c][n] + W[o][128+c]*x[b][c][n] + b[o]
// ---------------------------------------------------------------------------
__global__ __launch_bounds__(256) void out_kernel(const float* __restrict__ Md,
                                                  const float* __restrict__ x,
                                                  const float* __restrict__ W,
                                                  const float* __restrict__ bias,
                                                  float* __restrict__ out) {
  const int N = NDIM, O = 256;
  int bb = blockIdx.z;
  int o0 = blockIdx.y * 64;
  int n0 = blockIdx.x * 128;
  int t = threadIdx.x;
  int tx = t & 15, ty = t >> 4;
  int tx8 = tx * 8, ty4 = ty * 4;

  __shared__ float w1_s[32 * 64];    // [cc][o]
  __shared__ float w2_s[32 * 64];
  __shared__ float md_s[32 * 128];   // [cc][n]
  __shared__ float x_s[32 * 128];

  float acc[4][8];
#pragma unroll
  for (int i = 0; i < 4; ++i)
#pragma unroll
    for (int j = 0; j < 8; ++j) acc[i][j] = 0.f;

  for (int ch = 0; ch < 4; ++ch) {
    int c0 = ch * 32;
    __syncthreads();
#pragma unroll
    for (int p = 0; p < 2; ++p) {
      int i = t + 256 * p;  // 0..511
      int oo = i >> 3, q = i & 7;
      float4 v1 = *(const float4*)&W[(size_t)(o0 + oo) * 256 + c0 + q * 4];
      float4 v2 = *(const float4*)&W[(size_t)(o0 + oo) * 256 + 128 + c0 + q * 4];
      w1_s[(q * 4 + 0) * 64 + oo] = v1.x;
      w1_s[(q * 4 + 1) * 64 + oo] = v1.y;
      w1_s[(q * 4 + 2) * 64 + oo] = v1.z;
      w1_s[(q * 4 + 3) * 64 + oo] = v1.w;
      w2_s[(q * 4 + 0) * 64 + oo] = v2.x;
      w2_s[(q * 4 + 1) * 64 + oo] = v2.y;
      w2_s[(q * 4 + 2) * 64 + oo] = v2.z;
      w2_s[(q * 4 + 3) * 64 + oo] = v2.w;
    }
#pragma unroll
    for (int p = 0; p < 4; ++p) {
      int i = t + 256 * p;  // 0..1023
      int cc = i >> 5, q = (i & 31) * 4;
      *(float4*)&md_s[cc * 128 + q] =
          *(const float4*)&Md[(size_t)(bb * CDIM + c0 + cc) * N + n0 + q];
      *(float4*)&x_s[cc * 128 + q] =
          *(const float4*)&x[(size_t)(bb * CDIM + c0 + cc) * N + n0 + q];
    }
    __syncthreads();
#pragma unroll 8
    for (int cc = 0; cc < 32; ++cc) {
      float4 a1 = *(const float4*)&w1_s[cc * 64 + ty4];
      float4 a2 = *(const float4*)&w2_s[cc * 64 + ty4];
      float4 b1a = *(const float4*)&md_s[cc * 128 + tx8];
      float4 b1b = *(const float4*)&md_s[cc * 128 + tx8 + 4];
      float4 b2a = *(const float4*)&x_s[cc * 128 + tx8];
      float4 b2b = *(const float4*)&x_s[cc * 128 + tx8 + 4];
      float a1v[4] = {a1.x, a1.y, a1.z, a1.w};
      float a2v[4] = {a2.x, a2.y, a2.z, a2.w};
      float b1v[8] = {b1a.x, b1a.y, b1a.z, b1a.w, b1b.x, b1b.y, b1b.z, b1b.w};
      float b2v[8] = {b2a.x, b2a.y, b2a.z, b2a.w, b2b.x, b2b.y, b2b.z, b2b.w};
#pragma unroll
      for (int i = 0; i < 4; ++i)
#pragma unroll
        for (int j = 0; j < 8; ++j)
          acc[i][j] += a1v[i] * b1v[j] + a2v[i] * b2v[j];
    }
  }

#pragma unroll
  for (int i = 0; i < 4; ++i) {
    int o = o0 + ty4 + i;
    float bv = bias[o];
    float4 r0 = make_float4(acc[i][0] + bv, acc[i][1] + bv, acc[i][2] + bv, acc[i][3] + bv);
    float4 r1 = make_float4(acc[i][4] + bv, acc[i][5] + bv, acc[i][6] + bv, acc[i][7] + bv);
    float* po = out + (size_t)(bb * O + o) * N + n0 + tx8;
    *(float4*)&po[0] = r0;
    *(float4*)&po[4] = r1;
  }
}

// ---------------------------------------------------------------------------
extern "C" void kernel_launch(void* const* d_in, const int* in_sizes, int n_in,
                              void* d_out, int out_size, void* d_ws, size_t ws_size,
                              hipStream_t stream) {
  const float* x = (const float*)d_in[0];     // (4,128,4096) fp32
  const float* W = (const float*)d_in[1];     // (256,256,1,1) fp32
  const float* bias = (const float*)d_in[2];  // (256,) fp32
  float* out = (float*)d_out;                 // (4,256,4096) fp32

  // workspace carve (16B-aligned): xx 64K | idx 640K | Md 8M | sc (chunked)
  float* xx = (float*)d_ws;
  int* idx = (int*)((char*)d_ws + 65536);
  float* Md = (float*)((char*)d_ws + 65536 + 655360);
  const size_t fixed = 9109504;
  float* sc = (float*)((char*)d_ws + fixed);

  // sc row-chunk: largest power-of-2 rows R with R*4096*4 fitting in scratch
  int R = 4096;
  while ((size_t)R * NDIM * 4 + fixed > ws_size && R > 128) R >>= 1;

  xx_kernel<<<dim3(256), 256, 0, stream>>>(x, xx);
  for (int b = 0; b < BDIM; ++b) {
    for (int off = 0; off < NDIM; off += R) {
      score_kernel<<<dim3(R / 128, 32), 256, 0, stream>>>(x, xx, sc, b, off);
      scan_kernel<<<dim3(R / 4), 256, 0, stream>>>(sc, idx, b, off);
    }
  }
  gather_kernel<<<dim3(128, 4), 256, 0, stream>>>(x, idx, Md);
  out_kernel<<<dim3(32, 4, 4), 256, 0, stream>>>(Md, x, W, bias, out);
}

// Round 8
// 421.565 us; speedup vs baseline: 1.6993x; 1.1064x over previous
//
#include <hip/hip_runtime.h>
#include <stdint.h>

#define BDIM 4
#define CDIM 128
#define NDIM 4096
#define KSEL 10

typedef unsigned long long ull;

// CK-style global->LDS direct copy (16 B/lane).
__device__ __forceinline__ void async_cp16(void* lds, const void* g) {
  auto* gp = (const __attribute__((address_space(1))) unsigned int*)(uintptr_t)g;
  auto* lp = (__attribute__((address_space(3))) unsigned int*)(unsigned int)(uintptr_t)lds;
  __builtin_amdgcn_global_load_lds(gp, lp, 16, 0, 0);
}

// ---------------------------------------------------------------------------
// Kernel A: xx[b][n] = sum_c x[b][c][n]^2
// ---------------------------------------------------------------------------
__global__ __launch_bounds__(256) void xx_kernel(const float* __restrict__ x,
                                                 float* __restrict__ xx) {
  int t = threadIdx.x;
  int nl = t >> 2;
  int part = t & 3;
  int g = blockIdx.x * 64 + nl;      // 0..B*N-1
  int b = g >> 12;
  int n = g & (NDIM - 1);
  const float* xp = x + (size_t)b * CDIM * NDIM + n;
  float s = 0.f;
  int c0 = part * 32;
#pragma unroll
  for (int i = 0; i < 32; ++i) {
    float v = xp[(size_t)(c0 + i) * NDIM];
    s += v * v;
  }
  s += __shfl_xor(s, 1, 4);
  s += __shfl_xor(s, 2, 4);
  if (part == 0) xx[g] = s;
}

// ---------------------------------------------------------------------------
// Kernel S: score GEMM, SYMMETRY-HALVED. dot(x_n,x_m) is symmetric; only the
// -xx[col] correction differs between sc[n][m] and sc[m][n]. Grid = 528
// upper-triangular tile pairs (I<=J) instead of 1024: FMA work halves.
// Off-diagonal blocks write the tile twice: normal (2*acc - xx[m]) and
// transposed (2*acc - xx[n]); the transposed write is per-thread float4
// along the row dim (thread's 4 consecutive rows are contiguous there).
// Block 128x128, 256 threads, 8x8/thread. Staging/main loop = R7 (proven).
// ---------------------------------------------------------------------------
__global__ __launch_bounds__(256) void score_kernel(const float* __restrict__ x,
                                                    const float* __restrict__ xxg,
                                                    float* __restrict__ sc,
                                                    int bb) {
  const int N = NDIM;
  // triangular decode: block -> (I, J), I<=J  (uniform scalar loop, <=32 iter)
  int p = blockIdx.x;
  int I = 0;
  while (p >= 32 - I) { p -= 32 - I; ++I; }
  int J = I + p;
  int n0 = I * 128, m0 = J * 128;

  int t = threadIdx.x;
  int tx = t & 15, ty = t >> 4;
  int tx4 = tx * 4, ty4 = ty * 4;

  __shared__ float smem[10240];      // 40960 B (8192 used + pad; R5-R7 proven)
  float* xn_s = smem;                // [32][128]
  float* xm_s = smem + 4096;         // [32][128]

  const float* xb = x + (size_t)bb * CDIM * N;

  float acc[8][8];
#pragma unroll
  for (int i = 0; i < 8; ++i)
#pragma unroll
    for (int j = 0; j < 8; ++j) acc[i][j] = 0.f;

  int scc = t >> 5;                  // staging row base (0..7)
  int sq = (t & 31) * 4;             // staging col (float)

  for (int ch = 0; ch < 4; ++ch) {
    int c0 = ch * 32;
    __syncthreads();  // previous chunk's readers done
#pragma unroll
    for (int pp = 0; pp < 4; ++pp) {
      int i4 = t + 256 * pp;
      async_cp16(&xn_s[i4 * 4], &xb[(size_t)(c0 + scc + 8 * pp) * N + n0 + sq]);
    }
#pragma unroll
    for (int pp = 0; pp < 4; ++pp) {
      int i4 = t + 256 * pp;
      async_cp16(&xm_s[i4 * 4], &xb[(size_t)(c0 + scc + 8 * pp) * N + m0 + sq]);
    }
    __syncthreads();  // vmcnt(0) drain -> LDS valid

#pragma unroll 4
    for (int cc = 0; cc < 32; ++cc) {
      float4 a0 = *(const float4*)&xn_s[cc * 128 + ty4];
      float4 a1 = *(const float4*)&xn_s[cc * 128 + ty4 + 64];
      float4 b0 = *(const float4*)&xm_s[cc * 128 + tx4];
      float4 b1 = *(const float4*)&xm_s[cc * 128 + tx4 + 64];
      float av[8] = {a0.x, a0.y, a0.z, a0.w, a1.x, a1.y, a1.z, a1.w};
      float bv[8] = {b0.x, b0.y, b0.z, b0.w, b1.x, b1.y, b1.z, b1.w};
#pragma unroll
      for (int i = 0; i < 8; ++i)
#pragma unroll
        for (int j = 0; j < 8; ++j) acc[i][j] += av[i] * bv[j];
    }
  }

  const float* xxb = xxg + (size_t)bb * N;

  // epilogue 1: sc[n][m] = 2*acc - xx[m]
  {
    float4 w0 = *(const float4*)&xxb[m0 + tx4];
    float4 w1 = *(const float4*)&xxb[m0 + tx4 + 64];
    float wv[8] = {w0.x, w0.y, w0.z, w0.w, w1.x, w1.y, w1.z, w1.w};
#pragma unroll
    for (int i = 0; i < 8; ++i) {
      int row = n0 + ty4 + (i & 3) + (i >> 2) * 64;
      float* po = sc + (size_t)row * N + m0;
      *(float4*)&po[tx4] =
          make_float4(2.f * acc[i][0] - wv[0], 2.f * acc[i][1] - wv[1],
                      2.f * acc[i][2] - wv[2], 2.f * acc[i][3] - wv[3]);
      *(float4*)&po[tx4 + 64] =
          make_float4(2.f * acc[i][4] - wv[4], 2.f * acc[i][5] - wv[5],
                      2.f * acc[i][6] - wv[6], 2.f * acc[i][7] - wv[7]);
    }
  }

  // epilogue 2 (off-diag only): sc[m][n] = 2*acc - xx[n]
  if (J != I) {
    float4 u0 = *(const float4*)&xxb[n0 + ty4];
    float4 u1 = *(const float4*)&xxb[n0 + ty4 + 64];
    float uv[8] = {u0.x, u0.y, u0.z, u0.w, u1.x, u1.y, u1.z, u1.w};
#pragma unroll
    for (int j = 0; j < 8; ++j) {
      int col = m0 + tx4 + (j & 3) + (j >> 2) * 64;
      float* po = sc + (size_t)col * N + n0;
      *(float4*)&po[ty4] =
          make_float4(2.f * acc[0][j] - uv[0], 2.f * acc[1][j] - uv[1],
                      2.f * acc[2][j] - uv[2], 2.f * acc[3][j] - uv[3]);
      *(float4*)&po[ty4 + 64] =
          make_float4(2.f * acc[4][j] - uv[4], 2.f * acc[5][j] - uv[5],
                      2.f * acc[6][j] - uv[6], 2.f * acc[7][j] - uv[7]);
    }
  }
}

// ---------------------------------------------------------------------------
// Kernel T: top-10 scan (R7-proven: branchless top-2 + 10 argmax rounds,
// rare exact rescan below the extracted key).
// ---------------------------------------------------------------------------
__global__ __launch_bounds__(256) void scan_kernel(const float* __restrict__ sc,
                                                   int* __restrict__ idxout,
                                                   int bb) {
  int t = threadIdx.x;
  int lane = t & 63;
  int w = t >> 6;
  int row = blockIdx.x * 4 + w;
  const uint4* srow = (const uint4*)(sc + (size_t)row * NDIM);

  unsigned A0 = 4095u - (unsigned)(lane * 4);
  ull k1 = 0ull, k2 = 0ull;

#pragma unroll 4
  for (int j4 = 0; j4 < 16; ++j4) {
    uint4 q = srow[j4 * 64 + lane];
    unsigned vv[4] = {q.x, q.y, q.z, q.w};
#pragma unroll
    for (int e = 0; e < 4; ++e) {
      unsigned u = vv[e];
      unsigned mono = u ^ ((unsigned)(((int)u) >> 31) | 0x80000000u);
      ull key = ((ull)mono << 32) | (ull)(A0 - (unsigned)e - (unsigned)(j4 << 8));
      ull lo = k1 < key ? k1 : key;
      k1 = k1 < key ? key : k1;
      k2 = k2 < lo ? lo : k2;
    }
  }

  unsigned my = 0;
  for (int s = 0; s < KSEL; ++s) {
    ull mx = k1;
#pragma unroll
    for (int off = 1; off < 64; off <<= 1) {
      ull o = __shfl_xor(mx, off);
      if (o > mx) mx = o;
    }
    if (k1 == mx) {  // unique winner (keys unique, >0)
      if (k2 != 0ull) {
        k1 = k2;
        k2 = 0ull;
      } else {
        ull r1 = 0ull, r2 = 0ull;
        for (int j4 = 0; j4 < 16; ++j4) {
          uint4 q = srow[j4 * 64 + lane];
          unsigned vv[4] = {q.x, q.y, q.z, q.w};
#pragma unroll
          for (int e = 0; e < 4; ++e) {
            unsigned u = vv[e];
            unsigned mono = u ^ ((unsigned)(((int)u) >> 31) | 0x80000000u);
            ull key = ((ull)mono << 32) | (ull)(A0 - (unsigned)e - (unsigned)(j4 << 8));
            if (key < mx) {
              ull lo = r1 < key ? r1 : key;
              r1 = r1 < key ? key : r1;
              r2 = r2 < lo ? lo : r2;
            }
          }
        }
        k1 = r1;
        k2 = r2;
      }
    }
    if (lane == s) my = 4095u - (unsigned)(mx & 0xFFFFFFFFull);
  }
  if (lane < KSEL)
    idxout[((size_t)bb * NDIM + row) * KSEL + lane] = (int)my;
}

// ---------------------------------------------------------------------------
// Kernel C: Md[b][c][n] = mean_k x[b][c][idx[b][n][k]] - x[b][c][n]
// ---------------------------------------------------------------------------
__global__ __launch_bounds__(256) void gather_kernel(const float* __restrict__ x,
                                                     const int* __restrict__ idxg,
                                                     float* __restrict__ Md) {
  const int N = NDIM;
  int bb = blockIdx.y, c = blockIdx.x;
  __shared__ float row_s[NDIM];
  const float* rowg = x + (size_t)(bb * CDIM + c) * N;
  int t = threadIdx.x;
#pragma unroll
  for (int p = 0; p < 4; ++p) {
    int i4 = t + 256 * p;
    *(float4*)&row_s[i4 * 4] = *(const float4*)&rowg[i4 * 4];
  }
  __syncthreads();
  float* outp = Md + (size_t)(bb * CDIM + c) * N;
  const int* ib = idxg + (size_t)bb * N * KSEL;
  for (int p = 0; p < 16; ++p) {
    int n = t + 256 * p;
    const int* ip = ib + (size_t)n * KSEL;
    float s = 0.f;
#pragma unroll
    for (int k = 0; k < KSEL; ++k) s += row_s[ip[k]];
    outp[n] = s * 0.1f - row_s[n];
  }
}

// ---------------------------------------------------------------------------
// Kernel D: out[b][o][n] = sum_c W[o][c]*Md[b][c][n] + W[o][128+c]*x[b][c][n] + b[o]
// ---------------------------------------------------------------------------
__global__ __launch_bounds__(256) void out_kernel(const float* __restrict__ Md,
                                                  const float* __restrict__ x,
                                                  const float* __restrict__ W,
                                                  const float* __restrict__ bias,
                                                  float* __restrict__ out) {
  const int N = NDIM, O = 256;
  int bb = blockIdx.z;
  int o0 = blockIdx.y * 64;
  int n0 = blockIdx.x * 128;
  int t = threadIdx.x;
  int tx = t & 15, ty = t >> 4;
  int tx8 = tx * 8, ty4 = ty * 4;

  __shared__ float w1_s[32 * 64];    // [cc][o]
  __shared__ float w2_s[32 * 64];
  __shared__ float md_s[32 * 128];   // [cc][n]
  __shared__ float x_s[32 * 128];

  float acc[4][8];
#pragma unroll
  for (int i = 0; i < 4; ++i)
#pragma unroll
    for (int j = 0; j < 8; ++j) acc[i][j] = 0.f;

  for (int ch = 0; ch < 4; ++ch) {
    int c0 = ch * 32;
    __syncthreads();
#pragma unroll
    for (int p = 0; p < 2; ++p) {
      int i = t + 256 * p;  // 0..511
      int oo = i >> 3, q = i & 7;
      float4 v1 = *(const float4*)&W[(size_t)(o0 + oo) * 256 + c0 + q * 4];
      float4 v2 = *(const float4*)&W[(size_t)(o0 + oo) * 256 + 128 + c0 + q * 4];
      w1_s[(q * 4 + 0) * 64 + oo] = v1.x;
      w1_s[(q * 4 + 1) * 64 + oo] = v1.y;
      w1_s[(q * 4 + 2) * 64 + oo] = v1.z;
      w1_s[(q * 4 + 3) * 64 + oo] = v1.w;
      w2_s[(q * 4 + 0) * 64 + oo] = v2.x;
      w2_s[(q * 4 + 1) * 64 + oo] = v2.y;
      w2_s[(q * 4 + 2) * 64 + oo] = v2.z;
      w2_s[(q * 4 + 3) * 64 + oo] = v2.w;
    }
#pragma unroll
    for (int p = 0; p < 4; ++p) {
      int i = t + 256 * p;  // 0..1023
      int cc = i >> 5, q = (i & 31) * 4;
      *(float4*)&md_s[cc * 128 + q] =
          *(const float4*)&Md[(size_t)(bb * CDIM + c0 + cc) * N + n0 + q];
      *(float4*)&x_s[cc * 128 + q] =
          *(const float4*)&x[(size_t)(bb * CDIM + c0 + cc) * N + n0 + q];
    }
    __syncthreads();
#pragma unroll 8
    for (int cc = 0; cc < 32; ++cc) {
      float4 a1 = *(const float4*)&w1_s[cc * 64 + ty4];
      float4 a2 = *(const float4*)&w2_s[cc * 64 + ty4];
      float4 b1a = *(const float4*)&md_s[cc * 128 + tx8];
      float4 b1b = *(const float4*)&md_s[cc * 128 + tx8 + 4];
      float4 b2a = *(const float4*)&x_s[cc * 128 + tx8];
      float4 b2b = *(const float4*)&x_s[cc * 128 + tx8 + 4];
      float a1v[4] = {a1.x, a1.y, a1.z, a1.w};
      float a2v[4] = {a2.x, a2.y, a2.z, a2.w};
      float b1v[8] = {b1a.x, b1a.y, b1a.z, b1a.w, b1b.x, b1b.y, b1b.z, b1b.w};
      float b2v[8] = {b2a.x, b2a.y, b2a.z, b2a.w, b2b.x, b2b.y, b2b.z, b2b.w};
#pragma unroll
      for (int i = 0; i < 4; ++i)
#pragma unroll
        for (int j = 0; j < 8; ++j)
          acc[i][j] += a1v[i] * b1v[j] + a2v[i] * b2v[j];
    }
  }

#pragma unroll
  for (int i = 0; i < 4; ++i) {
    int o = o0 + ty4 + i;
    float bv = bias[o];
    float4 r0 = make_float4(acc[i][0] + bv, acc[i][1] + bv, acc[i][2] + bv, acc[i][3] + bv);
    float4 r1 = make_float4(acc[i][4] + bv, acc[i][5] + bv, acc[i][6] + bv, acc[i][7] + bv);
    float* po = out + (size_t)(bb * O + o) * N + n0 + tx8;
    *(float4*)&po[0] = r0;
    *(float4*)&po[4] = r1;
  }
}

// ---------------------------------------------------------------------------
extern "C" void kernel_launch(void* const* d_in, const int* in_sizes, int n_in,
                              void* d_out, int out_size, void* d_ws, size_t ws_size,
                              hipStream_t stream) {
  const float* x = (const float*)d_in[0];     // (4,128,4096) fp32
  const float* W = (const float*)d_in[1];     // (256,256,1,1) fp32
  const float* bias = (const float*)d_in[2];  // (256,) fp32
  float* out = (float*)d_out;                 // (4,256,4096) fp32

  // workspace carve: xx 64K | idx 640K | Md 8M | sc 64M (R7 proved ws fits)
  float* xx = (float*)d_ws;
  int* idx = (int*)((char*)d_ws + 65536);
  float* Md = (float*)((char*)d_ws + 65536 + 655360);
  float* sc = (float*)((char*)d_ws + 9109504);

  xx_kernel<<<dim3(256), 256, 0, stream>>>(x, xx);
  for (int b = 0; b < BDIM; ++b) {
    score_kernel<<<dim3(528), 256, 0, stream>>>(x, xx, sc, b);
    scan_kernel<<<dim3(1024), 256, 0, stream>>>(sc, idx, b);
  }
  gather_kernel<<<dim3(128, 4), 256, 0, stream>>>(x, idx, Md);
  out_kernel<<<dim3(32, 4, 4), 256, 0, stream>>>(Md, x, W, bias, out);
}

// Round 9
// 344.902 us; speedup vs baseline: 2.0770x; 1.2223x over previous
//
#include <hip/hip_runtime.h>
#include <stdint.h>

#define BDIM 4
#define CDIM 128
#define NDIM 4096
#define KSEL 10

typedef unsigned long long ull;

// CK-style global->LDS direct copy (16 B/lane).
__device__ __forceinline__ void async_cp16(void* lds, const void* g) {
  auto* gp = (const __attribute__((address_space(1))) unsigned int*)(uintptr_t)g;
  auto* lp = (__attribute__((address_space(3))) unsigned int*)(unsigned int)(uintptr_t)lds;
  __builtin_amdgcn_global_load_lds(gp, lp, 16, 0, 0);
}

// ---------------------------------------------------------------------------
// Kernel A: xx[b][n] = sum_c x[b][c][n]^2
// ---------------------------------------------------------------------------
__global__ __launch_bounds__(256) void xx_kernel(const float* __restrict__ x,
                                                 float* __restrict__ xx) {
  int t = threadIdx.x;
  int nl = t >> 2;
  int part = t & 3;
  int g = blockIdx.x * 64 + nl;      // 0..B*N-1
  int b = g >> 12;
  int n = g & (NDIM - 1);
  const float* xp = x + (size_t)b * CDIM * NDIM + n;
  float s = 0.f;
  int c0 = part * 32;
#pragma unroll
  for (int i = 0; i < 32; ++i) {
    float v = xp[(size_t)(c0 + i) * NDIM];
    s += v * v;
  }
  s += __shfl_xor(s, 1, 4);
  s += __shfl_xor(s, 2, 4);
  if (part == 0) xx[g] = s;
}

// ---------------------------------------------------------------------------
// Kernel W: WT[c][o] = W[o][c]  (256x256, one-time, L2-hot, ~3 us)
// ---------------------------------------------------------------------------
__global__ __launch_bounds__(256) void wtrans_kernel(const float* __restrict__ W,
                                                     float* __restrict__ WT) {
  int c = blockIdx.x, o = threadIdx.x;
  WT[c * 256 + o] = W[o * 256 + c];
}

// ---------------------------------------------------------------------------
// Kernel S: score GEMM, symmetry-halved (R8-proven), multi-batch grid.
// ---------------------------------------------------------------------------
__global__ __launch_bounds__(256) void score_kernel(const float* __restrict__ x,
                                                    const float* __restrict__ xxg,
                                                    float* __restrict__ scb,
                                                    int b0) {
  const int N = NDIM;
  int bb = b0 + blockIdx.y;
  float* sc = scb + (size_t)blockIdx.y * N * N;
  // triangular decode: block -> (I, J), I<=J
  int p = blockIdx.x;
  int I = 0;
  while (p >= 32 - I) { p -= 32 - I; ++I; }
  int J = I + p;
  int n0 = I * 128, m0 = J * 128;

  int t = threadIdx.x;
  int tx = t & 15, ty = t >> 4;
  int tx4 = tx * 4, ty4 = ty * 4;

  __shared__ float smem[10240];      // 40960 B (proven no-spill profile)
  float* xn_s = smem;                // [32][128]
  float* xm_s = smem + 4096;         // [32][128]

  const float* xb = x + (size_t)bb * CDIM * N;

  float acc[8][8];
#pragma unroll
  for (int i = 0; i < 8; ++i)
#pragma unroll
    for (int j = 0; j < 8; ++j) acc[i][j] = 0.f;

  for (int ch = 0; ch < 4; ++ch) {
    int c0 = ch * 32;
    __syncthreads();
#pragma unroll
    for (int pp = 0; pp < 4; ++pp) {
      int i4 = t + 256 * pp;
      async_cp16(&xn_s[i4 * 4], &xb[(size_t)(c0 + (i4 >> 5)) * N + n0 + (i4 & 31) * 4]);
    }
#pragma unroll
    for (int pp = 0; pp < 4; ++pp) {
      int i4 = t + 256 * pp;
      async_cp16(&xm_s[i4 * 4], &xb[(size_t)(c0 + (i4 >> 5)) * N + m0 + (i4 & 31) * 4]);
    }
    __syncthreads();

#pragma unroll 4
    for (int cc = 0; cc < 32; ++cc) {
      float4 a0 = *(const float4*)&xn_s[cc * 128 + ty4];
      float4 a1 = *(const float4*)&xn_s[cc * 128 + ty4 + 64];
      float4 b0 = *(const float4*)&xm_s[cc * 128 + tx4];
      float4 b1 = *(const float4*)&xm_s[cc * 128 + tx4 + 64];
      float av[8] = {a0.x, a0.y, a0.z, a0.w, a1.x, a1.y, a1.z, a1.w};
      float bv[8] = {b0.x, b0.y, b0.z, b0.w, b1.x, b1.y, b1.z, b1.w};
#pragma unroll
      for (int i = 0; i < 8; ++i)
#pragma unroll
        for (int j = 0; j < 8; ++j) acc[i][j] += av[i] * bv[j];
    }
  }

  const float* xxb = xxg + (size_t)bb * N;

  // epilogue 1: sc[n][m] = 2*acc - xx[m]
  {
    float4 w0 = *(const float4*)&xxb[m0 + tx4];
    float4 w1 = *(const float4*)&xxb[m0 + tx4 + 64];
    float wv[8] = {w0.x, w0.y, w0.z, w0.w, w1.x, w1.y, w1.z, w1.w};
#pragma unroll
    for (int i = 0; i < 8; ++i) {
      int row = n0 + ty4 + (i & 3) + (i >> 2) * 64;
      float* po = sc + (size_t)row * N + m0;
      *(float4*)&po[tx4] =
          make_float4(2.f * acc[i][0] - wv[0], 2.f * acc[i][1] - wv[1],
                      2.f * acc[i][2] - wv[2], 2.f * acc[i][3] - wv[3]);
      *(float4*)&po[tx4 + 64] =
          make_float4(2.f * acc[i][4] - wv[4], 2.f * acc[i][5] - wv[5],
                      2.f * acc[i][6] - wv[6], 2.f * acc[i][7] - wv[7]);
    }
  }

  // epilogue 2 (off-diag only): sc[m][n] = 2*acc - xx[n]
  if (J != I) {
    float4 u0 = *(const float4*)&xxb[n0 + ty4];
    float4 u1 = *(const float4*)&xxb[n0 + ty4 + 64];
    float uv[8] = {u0.x, u0.y, u0.z, u0.w, u1.x, u1.y, u1.z, u1.w};
#pragma unroll
    for (int j = 0; j < 8; ++j) {
      int col = m0 + tx4 + (j & 3) + (j >> 2) * 64;
      float* po = sc + (size_t)col * N + n0;
      *(float4*)&po[ty4] =
          make_float4(2.f * acc[0][j] - uv[0], 2.f * acc[1][j] - uv[1],
                      2.f * acc[2][j] - uv[2], 2.f * acc[3][j] - uv[3]);
      *(float4*)&po[ty4 + 64] =
          make_float4(2.f * acc[4][j] - uv[4], 2.f * acc[5][j] - uv[5],
                      2.f * acc[6][j] - uv[6], 2.f * acc[7][j] - uv[7]);
    }
  }
}

// ---------------------------------------------------------------------------
// Kernel T: top-10 scan (R7-proven), multi-batch grid.
// ---------------------------------------------------------------------------
__global__ __launch_bounds__(256) void scan_kernel(const float* __restrict__ scb,
                                                   int* __restrict__ idxout,
                                                   int b0) {
  int t = threadIdx.x;
  int lane = t & 63;
  int w = t >> 6;
  int row = blockIdx.x * 4 + w;
  int bb = b0 + blockIdx.y;
  const uint4* srow =
      (const uint4*)(scb + (size_t)blockIdx.y * NDIM * NDIM + (size_t)row * NDIM);

  unsigned A0 = 4095u - (unsigned)(lane * 4);
  ull k1 = 0ull, k2 = 0ull;

#pragma unroll 4
  for (int j4 = 0; j4 < 16; ++j4) {
    uint4 q = srow[j4 * 64 + lane];
    unsigned vv[4] = {q.x, q.y, q.z, q.w};
#pragma unroll
    for (int e = 0; e < 4; ++e) {
      unsigned u = vv[e];
      unsigned mono = u ^ ((unsigned)(((int)u) >> 31) | 0x80000000u);
      ull key = ((ull)mono << 32) | (ull)(A0 - (unsigned)e - (unsigned)(j4 << 8));
      ull lo = k1 < key ? k1 : key;
      k1 = k1 < key ? key : k1;
      k2 = k2 < lo ? lo : k2;
    }
  }

  unsigned my = 0;
  for (int s = 0; s < KSEL; ++s) {
    ull mx = k1;
#pragma unroll
    for (int off = 1; off < 64; off <<= 1) {
      ull o = __shfl_xor(mx, off);
      if (o > mx) mx = o;
    }
    if (k1 == mx) {  // unique winner
      if (k2 != 0ull) {
        k1 = k2;
        k2 = 0ull;
      } else {
        ull r1 = 0ull, r2 = 0ull;
        for (int j4 = 0; j4 < 16; ++j4) {
          uint4 q = srow[j4 * 64 + lane];
          unsigned vv[4] = {q.x, q.y, q.z, q.w};
#pragma unroll
          for (int e = 0; e < 4; ++e) {
            unsigned u = vv[e];
            unsigned mono = u ^ ((unsigned)(((int)u) >> 31) | 0x80000000u);
            ull key = ((ull)mono << 32) | (ull)(A0 - (unsigned)e - (unsigned)(j4 << 8));
            if (key < mx) {
              ull lo = r1 < key ? r1 : key;
              r1 = r1 < key ? key : r1;
              r2 = r2 < lo ? lo : r2;
            }
          }
        }
        k1 = r1;
        k2 = r2;
      }
    }
    if (lane == s) my = 4095u - (unsigned)(mx & 0xFFFFFFFFull);
  }
  if (lane < KSEL)
    idxout[((size_t)bb * NDIM + row) * KSEL + lane] = (int)my;
}

// ---------------------------------------------------------------------------
// Kernel C: Md[b][c][n] = mean_k x[b][c][idx[b][n][k]] - x[b][c][n]
// ---------------------------------------------------------------------------
__global__ __launch_bounds__(256) void gather_kernel(const float* __restrict__ x,
                                                     const int* __restrict__ idxg,
                                                     float* __restrict__ Md) {
  const int N = NDIM;
  int bb = blockIdx.y, c = blockIdx.x;
  __shared__ float row_s[NDIM];
  const float* rowg = x + (size_t)(bb * CDIM + c) * N;
  int t = threadIdx.x;
#pragma unroll
  for (int p = 0; p < 4; ++p) {
    int i4 = t + 256 * p;
    *(float4*)&row_s[i4 * 4] = *(const float4*)&rowg[i4 * 4];
  }
  __syncthreads();
  float* outp = Md + (size_t)(bb * CDIM + c) * N;
  const int* ib = idxg + (size_t)bb * N * KSEL;
  for (int p = 0; p < 16; ++p) {
    int n = t + 256 * p;
    const int* ip = ib + (size_t)n * KSEL;
    float s = 0.f;
#pragma unroll
    for (int k = 0; k < KSEL; ++k) s += row_s[ip[k]];
    outp[n] = s * 0.1f - row_s[n];
  }
}

// ---------------------------------------------------------------------------
// Kernel D v2: out[b][o][n] = sum_c WT[c][o]*Md[b][c][n]
//                           + sum_c WT[128+c][o]*x[b][c][n] + bias[o]
// Block 64o x 128n, 256 threads, 4x8/thread. K=256 in 8 chunks of 32
// (chunks 0-3: Md vs WT rows 0-127; chunks 4-7: x vs WT rows 128-255).
// All staging via async_cp16 on pre-transposed WT -> zero repack VALU,
// zero staging bank conflicts (R8 out had 6e6 conflicts from W repack).
// ---------------------------------------------------------------------------
__global__ __launch_bounds__(256) void out_kernel(const float* __restrict__ Md,
                                                  const float* __restrict__ x,
                                                  const float* __restrict__ WT,
                                                  const float* __restrict__ bias,
                                                  float* __restrict__ out) {
  const int N = NDIM, O = 256;
  int bb = blockIdx.z;
  int o0 = blockIdx.y * 64;
  int n0 = blockIdx.x * 128;
  int t = threadIdx.x;
  int tx = t & 15, ty = t >> 4;
  int tx4 = tx * 4, ty4 = ty * 4;

  __shared__ float smem[10240];      // 40960 B (24KB used + pad; proven profile)
  float* wt_s = smem;                // [32][64]
  float* src_s = smem + 2048;        // [32][128]

  float acc[4][8];
#pragma unroll
  for (int i = 0; i < 4; ++i)
#pragma unroll
    for (int j = 0; j < 8; ++j) acc[i][j] = 0.f;

  for (int ch = 0; ch < 8; ++ch) {
    const float* src = (ch < 4)
        ? Md + (size_t)(bb * CDIM + ch * 32) * N
        : x + (size_t)(bb * CDIM + (ch - 4) * 32) * N;
    __syncthreads();
#pragma unroll
    for (int p = 0; p < 2; ++p) {
      int i4 = t + 256 * p;  // 0..511: row = i4>>4 (0..31), col = (i4&15)*4
      async_cp16(&wt_s[i4 * 4], &WT[(size_t)(ch * 32 + (i4 >> 4)) * O + o0 + (i4 & 15) * 4]);
    }
#pragma unroll
    for (int p = 0; p < 4; ++p) {
      int i4 = t + 256 * p;  // 0..1023: row = i4>>5, col = (i4&31)*4
      async_cp16(&src_s[i4 * 4], &src[(size_t)(i4 >> 5) * N + n0 + (i4 & 31) * 4]);
    }
    __syncthreads();

#pragma unroll 4
    for (int cc = 0; cc < 32; ++cc) {
      float4 a = *(const float4*)&wt_s[cc * 64 + ty4];
      float4 b0 = *(const float4*)&src_s[cc * 128 + tx4];
      float4 b1 = *(const float4*)&src_s[cc * 128 + tx4 + 64];
      float av[4] = {a.x, a.y, a.z, a.w};
      float bv[8] = {b0.x, b0.y, b0.z, b0.w, b1.x, b1.y, b1.z, b1.w};
#pragma unroll
      for (int i = 0; i < 4; ++i)
#pragma unroll
        for (int j = 0; j < 8; ++j) acc[i][j] += av[i] * bv[j];
    }
  }

#pragma unroll
  for (int i = 0; i < 4; ++i) {
    int o = o0 + ty4 + i;
    float bv = bias[o];
    float* po = out + (size_t)(bb * O + o) * N + n0;
    *(float4*)&po[tx4] = make_float4(acc[i][0] + bv, acc[i][1] + bv,
                                     acc[i][2] + bv, acc[i][3] + bv);
    *(float4*)&po[tx4 + 64] = make_float4(acc[i][4] + bv, acc[i][5] + bv,
                                          acc[i][6] + bv, acc[i][7] + bv);
  }
}

// ---------------------------------------------------------------------------
extern "C" void kernel_launch(void* const* d_in, const int* in_sizes, int n_in,
                              void* d_out, int out_size, void* d_ws, size_t ws_size,
                              hipStream_t stream) {
  const float* x = (const float*)d_in[0];     // (4,128,4096) fp32
  const float* W = (const float*)d_in[1];     // (256,256,1,1) fp32
  const float* bias = (const float*)d_in[2];  // (256,) fp32
  float* out = (float*)d_out;                 // (4,256,4096) fp32

  // ws carve: xx 64K | idx 640K | Md 8M | sc (nb x 64M) ... | WT 256K at top
  float* xx = (float*)d_ws;
  int* idx = (int*)((char*)d_ws + 65536);
  float* Md = (float*)((char*)d_ws + 65536 + 655360);
  const size_t fixed = 9109504;
  float* sc = (float*)((char*)d_ws + fixed);
  size_t wt_off = (ws_size - 262144) & ~(size_t)255;
  float* WT = (float*)((char*)d_ws + wt_off);

  const size_t per_b = (size_t)NDIM * NDIM * 4;
  int nb = 1;
  if (fixed + 4 * per_b <= wt_off) nb = 4;
  else if (fixed + 2 * per_b <= wt_off) nb = 2;

  xx_kernel<<<dim3(256), 256, 0, stream>>>(x, xx);
  wtrans_kernel<<<dim3(256), 256, 0, stream>>>(W, WT);
  for (int b0 = 0; b0 < BDIM; b0 += nb) {
    score_kernel<<<dim3(528, nb), 256, 0, stream>>>(x, xx, sc, b0);
    scan_kernel<<<dim3(1024, nb), 256, 0, stream>>>(sc, idx, b0);
  }
  gather_kernel<<<dim3(128, 4), 256, 0, stream>>>(x, idx, Md);
  out_kernel<<<dim3(32, 4, 4), 256, 0, stream>>>(Md, x, WT, bias, out);
}